// Round 15
// baseline (137.222 us; speedup 1.0000x reference)
//
#include <hip/hip_runtime.h>

typedef unsigned short u16;
typedef __attribute__((ext_vector_type(8))) short bf16x8;
typedef __attribute__((ext_vector_type(4))) float f32x4;
typedef __attribute__((ext_vector_type(16))) float f32x16;
typedef __attribute__((ext_vector_type(4))) unsigned short u16x4;
typedef __attribute__((ext_vector_type(4))) unsigned int u32x4;

#define B_  2
#define S_  2048
#define H_  1024
#define NH_ 16
#define HD_ 64
#define MR_ (B_*S_)   /* 4096 rows */
#define K_  H_

__device__ __forceinline__ u16 f2bf(float f) {
  union { float f; unsigned u; } x; x.f = f;
  unsigned r = x.u + 0x7fffu + ((x.u >> 16) & 1u);
  return (u16)(r >> 16);
}

// packed f32x2 -> bf16x2 (RNE), single VALU op (no builtin on gfx950)
__device__ __forceinline__ unsigned cvtpk(float lo, float hi) {
  unsigned r;
  asm("v_cvt_pk_bf16_f32 %0, %1, %2" : "=v"(r) : "v"(lo), "v"(hi));
  return r;
}

// v_permlane32_swap_b32: a' = [a.lo32lanes | b.lo32lanes], b' = [a.hi32lanes | b.hi32lanes]
__device__ __forceinline__ void plswap(unsigned &a, unsigned &b) {
  asm("v_permlane32_swap_b32 %0, %1" : "+v"(a), "+v"(b));
}

__device__ __forceinline__ void gload16(const u16* g, u16* l) {
  __builtin_amdgcn_global_load_lds((const __attribute__((address_space(1))) void*)g,
                                   (__attribute__((address_space(3))) void*)l, 16, 0, 0);
}

// ---------------- prep: W transpose only (q/k/v cvt fused into gemm_qkv) ----------------
__global__ __launch_bounds__(256) void prep(const float* __restrict__ Wq, const float* __restrict__ Wk,
                                            const float* __restrict__ Wv, const float* __restrict__ Wo,
                                            u16* __restrict__ wt) {
  __shared__ float t[32][33];
  const int bid = blockIdx.x;
  const int z = bid >> 10;
  const int r = bid & 1023;
  const float* W = z == 0 ? Wq : z == 1 ? Wk : z == 2 ? Wv : Wo;
  u16* Wt = wt + (size_t)z * H_ * K_;
  const int n0 = (r & 31) * 32, k0 = (r >> 5) * 32;
  const int tx = threadIdx.x & 31, ty = threadIdx.x >> 5;  // ty 0..7
  #pragma unroll
  for (int i = 0; i < 4; i++) t[ty + 8*i][tx] = W[(size_t)(k0 + ty + 8*i) * H_ + n0 + tx];
  __syncthreads();
  #pragma unroll
  for (int i = 0; i < 4; i++) Wt[(size_t)(n0 + ty + 8*i) * K_ + k0 + tx] = f2bf(t[tx][ty + 8*i]);
}

// ======== 128x128 QKV GEMM, A fused-cvt from f32 (proven 2-barrier structure) ========
// 256 thr / 4 waves (2x2), per-wave 64x64, single-buffer 32KB LDS, slot-XOR swizzle.
// Per step: cvt+ds_write A_k (regs loaded LAST step) + B_k gload_lds + issue A_{k+1}
// f32 loads -> barrier (ONE drain: B DMA + A loads + ds_writes) -> MFMA -> barrier
// (nothing outstanding -> free). R14's bug: A-loads issued after 1st barrier made the
// 2nd barrier's vmcnt(0) a second full HBM-latency exposure per step.
template <int MODE>
__device__ __forceinline__ void qkv_body(const float* __restrict__ Af, const u16* __restrict__ Bt,
                                         const float* __restrict__ bias, float scale,
                                         u16* __restrict__ Obf, int m_tile, int n_tile,
                                         u16* ldsA, u16* ldsB) {
  const int tid = threadIdx.x;
  const int lane = tid & 63, wave = tid >> 6;
  const int wm = wave >> 1, wn = wave & 1;
  const int m0 = m_tile * 128, n0 = n_tile * 128;

  f32x4 acc[4][4] = {};

  const int srow = tid >> 3;                     // 0..31
  const int sslot = (tid & 7) ^ (srow & 7);      // logical k-slot (pre-swizzled source)
  const float* gaf = Af + (size_t)(m0 + srow) * K_ + sslot * 8;
  const u16* gb = Bt + (size_t)(n0 + srow) * K_ + sslot * 8;
  u16* la = ldsA + tid * 8;
  u16* lb = ldsB + tid * 8;

  const int fr = lane & 15;   // fragment row (A: m, B: n)
  const int kg = lane >> 4;   // k-group 0..3

  // prologue: issue A step-0 f32 loads
  float4 alo[4], ahi[4];
  #pragma unroll
  for (int j = 0; j < 4; j++) {
    const float* p = gaf + (size_t)(j * 32) * K_;
    alo[j] = *(const float4*)p;
    ahi[j] = *(const float4*)(p + 4);
  }

  for (int k0 = 0; k0 < K_; k0 += 64) {
    // cvt + LDS-write A_k (compiler waits the f32 loads); issue B_k DMA
    #pragma unroll
    for (int j = 0; j < 4; j++) {
      u32x4 wv = { cvtpk(alo[j].x, alo[j].y), cvtpk(alo[j].z, alo[j].w),
                   cvtpk(ahi[j].x, ahi[j].y), cvtpk(ahi[j].z, ahi[j].w) };
      *(u32x4*)(la + j * 2048) = wv;
      gload16(gb + (size_t)(j * 32) * K_ + k0, lb + j * 2048);
    }
    // issue A_{k+1} loads BEFORE the barrier: the single drain below covers them,
    // and the post-MFMA barrier then has no outstanding VMEM (R10 pattern).
    if (k0 + 64 < K_) {
      #pragma unroll
      for (int j = 0; j < 4; j++) {
        const float* p = gaf + (size_t)(j * 32) * K_ + k0 + 64;
        alo[j] = *(const float4*)p;
        ahi[j] = *(const float4*)(p + 4);
      }
    }
    __syncthreads();   // drains B DMA + A loads (vmcnt) + A ds_writes (lgkm) -- once

    #pragma unroll
    for (int kk = 0; kk < 2; kk++) {
      const int ps = (((kk << 2) | kg) ^ (fr & 7)) * 8;   // swizzled read
      bf16x8 a[4], b[4];
      #pragma unroll
      for (int mf = 0; mf < 4; mf++)
        a[mf] = *(const bf16x8*)&ldsA[(wm * 64 + mf * 16 + fr) * 64 + ps];
      #pragma unroll
      for (int nf = 0; nf < 4; nf++)
        b[nf] = *(const bf16x8*)&ldsB[(wn * 64 + nf * 16 + fr) * 64 + ps];
      #pragma unroll
      for (int mf = 0; mf < 4; mf++)
        #pragma unroll
        for (int nf = 0; nf < 4; nf++)
          acc[mf][nf] = __builtin_amdgcn_mfma_f32_16x16x32_bf16(a[mf], b[nf], acc[mf][nf], 0, 0, 0);
    }
    __syncthreads();
  }

  float bcol[4];
  #pragma unroll
  for (int nf = 0; nf < 4; nf++) bcol[nf] = bias[n0 + wn * 64 + nf * 16 + fr];

  if (MODE == 2) {
    // V^T store: out[((b*16+h)*64+d)*2048 + s], col=h*64+d, row=b*2048+s.
    #pragma unroll
    for (int mf = 0; mf < 4; mf++) {
      const int row0 = m0 + wm * 64 + mf * 16 + kg * 4;
      #pragma unroll
      for (int nf = 0; nf < 4; nf++) {
        const int col = n0 + wn * 64 + nf * 16 + fr;
        u16x4 o;
        #pragma unroll
        for (int r = 0; r < 4; r++) o[r] = f2bf(acc[mf][nf][r] + bcol[nf]);
        size_t idx = (((size_t)(col + ((row0 >> 11) << 10))) << 11) + (row0 & 2047);
        *(u16x4*)(Obf + idx) = o;
      }
    }
  } else {
    #pragma unroll
    for (int mf = 0; mf < 4; mf++)
      #pragma unroll
      for (int r = 0; r < 4; r++) {
        const int row = m0 + wm * 64 + mf * 16 + kg * 4 + r;
        #pragma unroll
        for (int nf = 0; nf < 4; nf++) {
          const int col = n0 + wn * 64 + nf * 16 + fr;
          Obf[(size_t)row * H_ + col] = f2bf((acc[mf][nf][r] + bcol[nf]) * scale);
        }
      }
  }
}

// XCD-chunked bijective swizzle over 256 blocks/plane (32 m x 8 n)
__device__ __forceinline__ void gemm_tiles(int &m_tile, int &n_tile) {
  const int bid = blockIdx.x + (blockIdx.y << 3);      // 0..255
  const int swz = ((bid & 7) << 5) + (bid >> 3);       // chunk = 32
  m_tile = swz >> 3;
  n_tile = swz & 7;
}

__global__ __launch_bounds__(256) void gemm_qkv(const float* __restrict__ q, const float* __restrict__ k,
                                                const float* __restrict__ v, const u16* __restrict__ wt,
                                                const float* __restrict__ b0, const float* __restrict__ b1,
                                                const float* __restrict__ b2,
                                                u16* __restrict__ QKo, u16* __restrict__ VTo) {
  __shared__ u16 ldsA[128 * 64];   // declared in kernel (R11 lesson: template would duplicate)
  __shared__ u16 ldsB[128 * 64];
  const int z = blockIdx.z;
  int mt, nt;
  gemm_tiles(mt, nt);
  const float* A = z == 0 ? q : z == 1 ? k : v;
  const u16* Bt = wt + (size_t)z * H_ * K_;
  if (z == 2) {
    qkv_body<2>(A, Bt, b2, 1.0f, VTo, mt, nt, ldsA, ldsB);
  } else {
    const float* bias = z == 0 ? b0 : b1;
    // fold 1/sqrt(HD) AND log2(e) into Q so softmax uses raw v_exp_f32 (exp2)
    const float scale = z == 0 ? 0.18033688011112042f : 1.0f;
    qkv_body<0>(A, Bt, bias, scale, QKo + (size_t)z * MR_ * H_, mt, nt, ldsA, ldsB);
  }
}

// ---------------- 128x128 GEMM body (proven) -- used by gemm_out only ----------------
__device__ __forceinline__ void gemm_body_f32(const u16* __restrict__ A, const u16* __restrict__ Bt,
                                              const float* __restrict__ bias, float* __restrict__ Of,
                                              int m_tile, int n_tile) {
  __shared__ u16 ldsA[128 * 64];
  __shared__ u16 ldsB[128 * 64];
  const int tid = threadIdx.x;
  const int lane = tid & 63, wave = tid >> 6;
  const int wm = wave >> 1, wn = wave & 1;
  const int m0 = m_tile * 128, n0 = n_tile * 128;

  f32x4 acc[4][4] = {};

  const int srow = tid >> 3;                     // 0..31
  const int sslot = (tid & 7) ^ (srow & 7);      // logical k-slot to fetch (pre-swizzled source)
  const u16* ga = A + (size_t)(m0 + srow) * K_ + sslot * 8;
  const u16* gb = Bt + (size_t)(n0 + srow) * K_ + sslot * 8;
  u16* la = ldsA + tid * 8;
  u16* lb = ldsB + tid * 8;

  const int fr = lane & 15;   // fragment row (A: m, B: n)
  const int kg = lane >> 4;   // k-group 0..3

  for (int k0 = 0; k0 < K_; k0 += 64) {
    #pragma unroll
    for (int j = 0; j < 4; j++) gload16(ga + (size_t)(j * 32) * K_ + k0, la + j * 2048);
    #pragma unroll
    for (int j = 0; j < 4; j++) gload16(gb + (size_t)(j * 32) * K_ + k0, lb + j * 2048);
    __syncthreads();

    #pragma unroll
    for (int kk = 0; kk < 2; kk++) {
      const int ps = (((kk << 2) | kg) ^ (fr & 7)) * 8;   // swizzled read
      bf16x8 a[4], b[4];
      #pragma unroll
      for (int mf = 0; mf < 4; mf++)
        a[mf] = *(const bf16x8*)&ldsA[(wm * 64 + mf * 16 + fr) * 64 + ps];
      #pragma unroll
      for (int nf = 0; nf < 4; nf++)
        b[nf] = *(const bf16x8*)&ldsB[(wn * 64 + nf * 16 + fr) * 64 + ps];
      #pragma unroll
      for (int mf = 0; mf < 4; mf++)
        #pragma unroll
        for (int nf = 0; nf < 4; nf++)
          acc[mf][nf] = __builtin_amdgcn_mfma_f32_16x16x32_bf16(a[mf], b[nf], acc[mf][nf], 0, 0, 0);
    }
    __syncthreads();
  }

  float bcol[4];
  #pragma unroll
  for (int nf = 0; nf < 4; nf++) bcol[nf] = bias[n0 + wn * 64 + nf * 16 + fr];
  #pragma unroll
  for (int mf = 0; mf < 4; mf++)
    #pragma unroll
    for (int r = 0; r < 4; r++) {
      const int row = m0 + wm * 64 + mf * 16 + kg * 4 + r;
      #pragma unroll
      for (int nf = 0; nf < 4; nf++) {
        const int col = n0 + wn * 64 + nf * 16 + fr;
        Of[(size_t)row * H_ + col] = acc[mf][nf][r] + bcol[nf];
      }
    }
}

__global__ __launch_bounds__(256) void gemm_out(const u16* __restrict__ ctx, const u16* __restrict__ wot,
                                                const float* __restrict__ bo, float* __restrict__ out) {
  const int bid = blockIdx.x + (blockIdx.y << 3);      // 0..255
  const int swz = ((bid & 7) << 5) + (bid >> 3);       // XCD-chunked
  gemm_body_f32(ctx, wot, bo, out, swz >> 3, swz & 7);
}

// ---------------- flash attention: 8 waves, in-block split-KV (unchanged) ----------------
__global__ __launch_bounds__(512, 4) void attn(const u16* __restrict__ qp, const u16* __restrict__ kp,
                                               const u16* __restrict__ vt, u16* __restrict__ ctx) {
  __shared__ u16 Kl[2][2][64 * 64];   // [group][buf][s][d-slot], phys_slot = slot ^ (s&7)
  __shared__ u16 Vl[2][2][64 * 64];   // [group][buf][d][s-slot], phys_slot = slot ^ (d&7)
  __shared__ float mlbuf[2][4][32][2];
  // XCD-chunked bijective swizzle: 16 q-tiles per bh stay on one XCD
  const int bid = blockIdx.x + (blockIdx.y << 4);
  const int swz = ((bid & 7) << 6) + (bid >> 3);
  const int bh = swz >> 4;
  const int b = bh >> 4, h = bh & 15;
  const int q0 = (swz & 15) * 128;
  const int tid = threadIdx.x;
  const int g0 = tid >> 8;            // kv-half group
  const int gt = tid & 255;           // thread id within group
  const int w = (tid >> 6) & 3;       // wave within group
  const int l = tid & 63;
  const int ql = l & 31, hi = l >> 5;

  const u16* Q   = qp + (size_t)b * S_ * H_ + h * HD_;
  const u16* Kb  = kp + (size_t)b * S_ * H_ + h * HD_;
  const u16* Vtb = vt + (size_t)bh * HD_ * S_;
  u16* O = ctx + (size_t)b * S_ * H_ + h * HD_;

  const int srow = gt >> 3;                   // 0..31
  const int sslot = (gt & 7) ^ (srow & 7);    // logical slot to fetch (pre-swizzled source)
  const int sbase = g0 << 10;                 // this group's kv offset

  // Q row base (fragments reloaded per iter; addresses loop-invariant, L1-resident)
  const u16* Qrow = Q + (size_t)(q0 + w * 32 + ql) * H_;

  f32x16 oacc0 = {}, oacc1 = {};       // C[q][d], dt=0,1 ; rows q=(r&3)+8*(r>>2)+4*hi, col d=dt*32+ql
  float m_run = -1e30f, l_run = 0.f;   // state for q-col = ql (mirrored on lane pair)

  // prologue: stage tile 0 into buffer 0
  #pragma unroll
  for (int j = 0; j < 2; j++) {
    gload16(Kb + (size_t)(sbase + srow + 32 * j) * H_ + sslot * 8,
            &Kl[g0][0][0] + j * 2048 + gt * 8);
    gload16(Vtb + (size_t)(srow + 32 * j) * S_ + sbase + sslot * 8,
            &Vl[g0][0][0] + j * 2048 + gt * 8);
  }

  for (int it = 0; it < 16; ++it) {
    const int s0 = sbase + it * 64, cur = it & 1;
    __syncthreads();   // staged tile visible
    if (it + 1 < 16) {
      #pragma unroll
      for (int j = 0; j < 2; j++) {
        gload16(Kb + (size_t)(s0 + 64 + srow + 32 * j) * H_ + sslot * 8,
                &Kl[g0][cur ^ 1][0] + j * 2048 + gt * 8);
        gload16(Vtb + (size_t)(srow + 32 * j) * S_ + s0 + 64 + sslot * 8,
                &Vl[g0][cur ^ 1][0] + j * 2048 + gt * 8);
      }
    }
    // swapped QK^T: sc_st = mfma32(K_frag, Q_frag). D[s][q]: q=l&31, s=st*32+(r&3)+8*(r>>2)+4*hi
    f32x16 sc0 = {}, sc1 = {};
    __builtin_amdgcn_s_setprio(1);
    #pragma unroll
    for (int ds = 0; ds < 4; ds++) {
      const int sl = ((ds * 2 + hi) ^ (ql & 7)) << 3;
      bf16x8 qd = *(const bf16x8*)&Qrow[ds * 16 + hi * 8];   // re-materialized (L1 hit)
      bf16x8 k0 = *(const bf16x8*)&Kl[g0][cur][ql * 64 + sl];
      bf16x8 k1 = *(const bf16x8*)&Kl[g0][cur][(32 + ql) * 64 + sl];
      sc0 = __builtin_amdgcn_mfma_f32_32x32x16_bf16(k0, qd, sc0, 0, 0, 0);
      sc1 = __builtin_amdgcn_mfma_f32_32x32x16_bf16(k1, qd, sc1, 0, 0, 0);
    }
    __builtin_amdgcn_s_setprio(0);
    // tree max over 32 in-register scores, then one cross-half reduce
    float t4[8];
    #pragma unroll
    for (int g = 0; g < 4; g++) {
      t4[g]     = fmaxf(fmaxf(sc0[4*g], sc0[4*g+1]), fmaxf(sc0[4*g+2], sc0[4*g+3]));
      t4[4 + g] = fmaxf(fmaxf(sc1[4*g], sc1[4*g+1]), fmaxf(sc1[4*g+2], sc1[4*g+3]));
    }
    float tmax = fmaxf(fmaxf(fmaxf(t4[0], t4[1]), fmaxf(t4[2], t4[3])),
                       fmaxf(fmaxf(t4[4], t4[5]), fmaxf(t4[6], t4[7])));
    tmax = fmaxf(tmax, __shfl_xor(tmax, 32, 64));
    // defer-max (THR=8 log2 units)
    if (!__all(tmax <= m_run + 8.0f)) {
      const float mn = fmaxf(m_run, tmax);
      const float sf = __builtin_amdgcn_exp2f(m_run - mn);
      m_run = mn;
      l_run *= sf;
      #pragma unroll
      for (int r = 0; r < 16; r++) {
        const float sfq = __shfl(sf, (r & 3) + 8 * (r >> 2) + 4 * hi, 64);
        oacc0[r] *= sfq;
        oacc1[r] *= sfq;
      }
    }
    // p = exp2(sc - m_run); psum; cvt_pk packs (pk[st][g] covers s' = 8g+4*hi+(0..3))
    float ps4[8];
    #pragma unroll
    for (int g = 0; g < 4; g++) {
      #pragma unroll
      for (int m = 0; m < 4; m++) {
        sc0[4*g+m] = __builtin_amdgcn_exp2f(sc0[4*g+m] - m_run);
        sc1[4*g+m] = __builtin_amdgcn_exp2f(sc1[4*g+m] - m_run);
      }
      ps4[g]     = (sc0[4*g] + sc0[4*g+1]) + (sc0[4*g+2] + sc0[4*g+3]);
      ps4[4 + g] = (sc1[4*g] + sc1[4*g+1]) + (sc1[4*g+2] + sc1[4*g+3]);
    }
    float psum = ((ps4[0] + ps4[1]) + (ps4[2] + ps4[3])) + ((ps4[4] + ps4[5]) + (ps4[6] + ps4[7]));
    psum += __shfl_xor(psum, 32, 64);
    l_run += psum;
    uint2 pk0[4], pk1[4];
    #pragma unroll
    for (int g = 0; g < 4; g++) {
      pk0[g].x = cvtpk(sc0[4*g], sc0[4*g+1]);  pk0[g].y = cvtpk(sc0[4*g+2], sc0[4*g+3]);
      pk1[g].x = cvtpk(sc1[4*g], sc1[4*g+1]);  pk1[g].y = cvtpk(sc1[4*g+2], sc1[4*g+3]);
    }
    // PV: A = P[q][s] assembled via permlane32_swap; B = V^T[d][s] from LDS
    __builtin_amdgcn_s_setprio(1);
    #pragma unroll
    for (int ks = 0; ks < 4; ks++) {
      const int ga = (ks & 1) * 2;
      unsigned x0, y0, x1, y1;
      if (ks < 2) { x0 = pk0[ga].x; y0 = pk0[ga].y; x1 = pk0[ga+1].x; y1 = pk0[ga+1].y; }
      else        { x0 = pk1[ga].x; y0 = pk1[ga].y; x1 = pk1[ga+1].x; y1 = pk1[ga+1].y; }
      plswap(x0, x1);   // x0 -> j0..1 merged, x1 -> j4..5
      plswap(y0, y1);   // y0 -> j2..3,        y1 -> j6..7
      u32x4 fu = { x0, y0, x1, y1 };
      const bf16x8 pfrag = __builtin_bit_cast(bf16x8, fu);
      #pragma unroll
      for (int dt = 0; dt < 2; dt++) {
        const int d = dt * 32 + ql;
        bf16x8 vf = *(const bf16x8*)&Vl[g0][cur][d * 64 + (((ks * 2 + hi) ^ (d & 7)) << 3)];
        if (dt == 0) oacc0 = __builtin_amdgcn_mfma_f32_32x32x16_bf16(pfrag, vf, oacc0, 0, 0, 0);
        else         oacc1 = __builtin_amdgcn_mfma_f32_32x32x16_bf16(pfrag, vf, oacc1, 0, 0, 0);
      }
    }
    __builtin_amdgcn_s_setprio(0);
  }

  // -------- merge the two kv-half partials --------
  if (l < 32) { mlbuf[g0][w][ql][0] = m_run; mlbuf[g0][w][ql][1] = l_run; }
  __syncthreads();   // ml visible; also: all LDS K/V reads done -> Kl reusable
  const float m_o = mlbuf[g0 ^ 1][w][ql][0];
  const float l_o = mlbuf[g0 ^ 1][w][ql][1];
  const float m_tot = fmaxf(m_run, m_o);
  const float a_s = __builtin_amdgcn_exp2f(m_run - m_tot);
  const float rinv = 1.0f / (l_run * a_s + l_o * __builtin_amdgcn_exp2f(m_o - m_tot));
  // broadcast BOTH a_s and rinv to the oacc row owners (row q=qi, NOT ql)
  float ar[16], rr[16];
  #pragma unroll
  for (int r = 0; r < 16; r++) {
    const int qi = (r & 3) + 8 * (r >> 2) + 4 * hi;
    ar[r] = __shfl(a_s, qi, 64);
    rr[r] = __shfl(rinv, qi, 64);
  }

  float* cb = (float*)(&Kl[0][0][0]);          // 32 KB scratch (retired K tiles)
  float* cw = cb + w * 2048 + l;
  if (g0 == 1) {
    #pragma unroll
    for (int r = 0; r < 16; r++) {
      cw[r * 64]        = oacc0[r] * ar[r];
      cw[(16 + r) * 64] = oacc1[r] * ar[r];
    }
  }
  __syncthreads();
  if (g0 == 0) {
    #pragma unroll
    for (int r = 0; r < 16; r++) {
      const int qi = (r & 3) + 8 * (r >> 2) + 4 * hi;
      const int row = q0 + w * 32 + qi;
      O[(size_t)row * H_ + ql]      = f2bf((oacc0[r] * ar[r] + cw[r * 64]) * rr[r]);
      O[(size_t)row * H_ + 32 + ql] = f2bf((oacc1[r] * ar[r] + cw[(16 + r) * 64]) * rr[r]);
    }
  }
}

extern "C" void kernel_launch(void* const* d_in, const int* in_sizes, int n_in,
                              void* d_out, int out_size, void* d_ws, size_t ws_size,
                              hipStream_t stream) {
  const float* q  = (const float*)d_in[0];
  const float* k  = (const float*)d_in[1];
  const float* v  = (const float*)d_in[2];
  const float* Wq = (const float*)d_in[3];
  const float* bq = (const float*)d_in[4];
  const float* Wk = (const float*)d_in[5];
  const float* bk = (const float*)d_in[6];
  const float* Wv = (const float*)d_in[7];
  const float* bv = (const float*)d_in[8];
  const float* Wo = (const float*)d_in[9];
  const float* bo = (const float*)d_in[10];
  float* out = (float*)d_out;

  char* ws = (char*)d_ws;
  const size_t MB = 1024 * 1024;
  u16* ctx  = (u16*)(ws);             // attn output: 8MB         [0,8)
  u16* wt   = (u16*)(ws + 24 * MB);   // 4 x 2MB transposed W     [24,32)
  u16* qkp  = (u16*)(ws + 32 * MB);   // qp,kp: 2 x 8MB           [32,48)
  u16* vtp  = (u16*)(ws + 48 * MB);   // V^T [bh][d][s]: 8MB      [48,56)

  prep    <<<dim3(4096),      256, 0, stream>>>(Wq, Wk, Wv, Wo, wt);
  gemm_qkv<<<dim3(8, 32, 3),  256, 0, stream>>>(q, k, v, wt, bq, bk, bv, qkp, vtp);
  attn    <<<dim3(16, 32),    512, 0, stream>>>(qkp, qkp + (size_t)MR_ * H_, vtp, ctx);
  gemm_out<<<dim3(8, 32, 1),  256, 0, stream>>>(ctx, wt + (size_t)3 * H_ * K_, bo, out);
}

// Round 16
// 131.282 us; speedup vs baseline: 1.0452x; 1.0452x over previous
//
#include <hip/hip_runtime.h>

typedef unsigned short u16;
typedef __attribute__((ext_vector_type(8))) short bf16x8;
typedef __attribute__((ext_vector_type(4))) float f32x4;
typedef __attribute__((ext_vector_type(16))) float f32x16;
typedef __attribute__((ext_vector_type(4))) unsigned short u16x4;
typedef __attribute__((ext_vector_type(4))) unsigned int u32x4;

#define B_  2
#define S_  2048
#define H_  1024
#define NH_ 16
#define HD_ 64
#define MR_ (B_*S_)   /* 4096 rows */
#define K_  H_

__device__ __forceinline__ u16 f2bf(float f) {
  union { float f; unsigned u; } x; x.f = f;
  unsigned r = x.u + 0x7fffu + ((x.u >> 16) & 1u);
  return (u16)(r >> 16);
}

// packed f32x2 -> bf16x2 (RNE), single VALU op (no builtin on gfx950)
__device__ __forceinline__ unsigned cvtpk(float lo, float hi) {
  unsigned r;
  asm("v_cvt_pk_bf16_f32 %0, %1, %2" : "=v"(r) : "v"(lo), "v"(hi));
  return r;
}

// v_permlane32_swap_b32: a' = [a.lo32lanes | b.lo32lanes], b' = [a.hi32lanes | b.hi32lanes]
__device__ __forceinline__ void plswap(unsigned &a, unsigned &b) {
  asm("v_permlane32_swap_b32 %0, %1" : "+v"(a), "+v"(b));
}

__device__ __forceinline__ void gload16(const u16* g, u16* l) {
  __builtin_amdgcn_global_load_lds((const __attribute__((address_space(1))) void*)g,
                                   (__attribute__((address_space(3))) void*)l, 16, 0, 0);
}

// ---------------- prep: cvt q,k,v f32->bf16 (blocks 0..12287) + W transpose (12288..16383) ----------------
__global__ __launch_bounds__(256) void prep(const float* __restrict__ q, const float* __restrict__ k,
                                            const float* __restrict__ v, const float* __restrict__ Wq,
                                            const float* __restrict__ Wk, const float* __restrict__ Wv,
                                            const float* __restrict__ Wo, u16* __restrict__ dst,
                                            u16* __restrict__ wt) {
  __shared__ float t[32][33];
  const int bid = blockIdx.x;
  if (bid < 12288) {
    const int z = bid >> 12;
    const float* src = z == 0 ? q : z == 1 ? k : v;
    u16* d = dst + (size_t)z * MR_ * H_;
    size_t i = ((size_t)(bid & 4095) * 256 + threadIdx.x) * 4;
    float4 f = *(const float4*)(src + i);
    u16x4 o = { f2bf(f.x), f2bf(f.y), f2bf(f.z), f2bf(f.w) };
    *(u16x4*)(d + i) = o;
  } else {
    const int r = bid - 12288;
    const int z = r >> 10;
    const float* W = z == 0 ? Wq : z == 1 ? Wk : z == 2 ? Wv : Wo;
    u16* Wt = wt + (size_t)z * H_ * K_;
    const int n0 = (r & 31) * 32, k0 = ((r >> 5) & 31) * 32;
    const int tx = threadIdx.x & 31, ty = threadIdx.x >> 5;  // ty 0..7
    #pragma unroll
    for (int i = 0; i < 4; i++) t[ty + 8*i][tx] = W[(size_t)(k0 + ty + 8*i) * H_ + n0 + tx];
    __syncthreads();
    #pragma unroll
    for (int i = 0; i < 4; i++) Wt[(size_t)(n0 + ty + 8*i) * K_ + k0 + tx] = f2bf(t[tx][ty + 8*i]);
  }
}

// ============ 256x256 phase-interleaved GEMM (T3-style) for QKV ============
// BM=BN=256, BK=64, 512 thr = 8 waves (2M x 4N); per-wave 128x64 out = acc[8][4].
// LDS 128KB dbuf (declared in kernel -- template instantiations would each get
// their own copy otherwise). Slot-XOR swizzle, linear gload_lds dest. 4 phases/
// K-step: {ds_read subtile | front-loaded stage} -> raw barrier -> setprio(1)
// 16 MFMA setprio(0) -> raw barrier. vmcnt(0) only at step boundary.
template <int MODE>
__device__ __forceinline__ void body256(const u16* __restrict__ A, const u16* __restrict__ Bt,
                                        const float* __restrict__ bias, float scale,
                                        u16* __restrict__ Obf, int mt, int nt,
                                        u16* lAbase, u16* lBbase) {
  const int tid = threadIdx.x;
  const int lane = tid & 63, wave = tid >> 6;
  const int wm = wave >> 2, wn = wave & 3;
  const int fr = lane & 15, kg = lane >> 4;
  const int m0 = mt * 256, n0 = nt * 256;

  const int srow = tid >> 3;                   // 0..63
  const int sslot = (tid & 7) ^ (srow & 7);    // logical slot to fetch (pre-swizzled source)
  const u16* ga = A + (size_t)(m0 + srow) * K_ + sslot * 8;
  const u16* gb = Bt + (size_t)(n0 + srow) * K_ + sslot * 8;

  f32x4 acc[8][4] = {};

  // prologue: stage step 0 into buf 0
  #pragma unroll
  for (int j = 0; j < 4; j++) {
    gload16(ga + (size_t)(j * 64) * K_, lAbase + j * 4096 + tid * 8);
    gload16(gb + (size_t)(j * 64) * K_, lBbase + j * 4096 + tid * 8);
  }
  asm volatile("s_waitcnt vmcnt(0)" ::: "memory");
  __builtin_amdgcn_s_barrier();
  __builtin_amdgcn_sched_barrier(0);

  for (int s = 0; s < 16; ++s) {
    const int cur = s & 1;
    const u16* Acur = lAbase + cur * 16384;
    const u16* Bcur = lBbase + cur * 16384;
    u16* Anxt = lAbase + (cur ^ 1) * 16384;
    u16* Bnxt = lBbase + (cur ^ 1) * 16384;
    const size_t knext = (size_t)(s + 1) * 64;
    bf16x8 af[4][2];
    #pragma unroll
    for (int p = 0; p < 4; ++p) {
      const int mh = p >> 1, nh = p & 1;
      if ((p & 1) == 0) {   // new A-half (kept across 2 phases)
        #pragma unroll
        for (int mf2 = 0; mf2 < 4; ++mf2)
          #pragma unroll
          for (int kk = 0; kk < 2; ++kk)
            af[mf2][kk] = *(const bf16x8*)&Acur[(wm * 128 + mh * 64 + mf2 * 16 + fr) * 64 +
                                                ((((kk << 2) | kg) ^ (fr & 7)) << 3)];
      }
      bf16x8 bfr[2][2];
      #pragma unroll
      for (int nf2 = 0; nf2 < 2; ++nf2)
        #pragma unroll
        for (int kk = 0; kk < 2; ++kk)
          bfr[nf2][kk] = *(const bf16x8*)&Bcur[(wn * 64 + nh * 32 + nf2 * 16 + fr) * 64 +
                                               ((((kk << 2) | kg) ^ (fr & 7)) << 3)];
      if (s < 15 && p < 2) {   // front-load next-step staging (phases 0,1)
        #pragma unroll
        for (int jj = 0; jj < 2; ++jj) {
          const int j = p * 2 + jj;
          gload16(ga + (size_t)(j * 64) * K_ + knext, Anxt + j * 4096 + tid * 8);
          gload16(gb + (size_t)(j * 64) * K_ + knext, Bnxt + j * 4096 + tid * 8);
        }
      }
      __builtin_amdgcn_s_barrier();          // align waves entering MFMA cluster
      __builtin_amdgcn_s_setprio(1);
      #pragma unroll
      for (int mf2 = 0; mf2 < 4; ++mf2)
        #pragma unroll
        for (int nf2 = 0; nf2 < 2; ++nf2)
          #pragma unroll
          for (int kk = 0; kk < 2; ++kk)
            acc[mh * 4 + mf2][nh * 2 + nf2] = __builtin_amdgcn_mfma_f32_16x16x32_bf16(
                af[mf2][kk], bfr[nf2][kk], acc[mh * 4 + mf2][nh * 2 + nf2], 0, 0, 0);
      __builtin_amdgcn_s_setprio(0);
      if (p < 3) {
        __builtin_amdgcn_s_barrier();
      } else {
        // step boundary: all waves drain their gloads, then align -> next-step ds_reads safe
        asm volatile("s_waitcnt vmcnt(0)" ::: "memory");
        __builtin_amdgcn_s_barrier();
        __builtin_amdgcn_sched_barrier(0);
      }
    }
  }

  float bcol[4];
  #pragma unroll
  for (int nf = 0; nf < 4; nf++) bcol[nf] = bias[n0 + wn * 64 + nf * 16 + fr];

  if (MODE == 2) {
    // V^T store: out[((b*16+h)*64+d)*2048 + s], col=h*64+d, row=b*2048+s.
    #pragma unroll
    for (int mf = 0; mf < 8; mf++) {
      const int row0 = m0 + wm * 128 + mf * 16 + kg * 4;
      #pragma unroll
      for (int nf = 0; nf < 4; nf++) {
        const int col = n0 + wn * 64 + nf * 16 + fr;
        u16x4 o;
        #pragma unroll
        for (int r = 0; r < 4; r++) o[r] = f2bf(acc[mf][nf][r] + bcol[nf]);
        size_t idx = (((size_t)(col + ((row0 >> 11) << 10))) << 11) + (row0 & 2047);
        *(u16x4*)(Obf + idx) = o;
      }
    }
  } else {
    #pragma unroll
    for (int mf = 0; mf < 8; mf++)
      #pragma unroll
      for (int r = 0; r < 4; r++) {
        const int row = m0 + wm * 128 + mf * 16 + kg * 4 + r;
        #pragma unroll
        for (int nf = 0; nf < 4; nf++) {
          const int col = n0 + wn * 64 + nf * 16 + fr;
          Obf[(size_t)row * H_ + col] = f2bf((acc[mf][nf][r] + bcol[nf]) * scale);
        }
      }
  }
}

// grid (8,8,3): xcd = blockIdx.x (64 blocks/plane, 8|64); XCD x owns m_tiles [2x,2x+2)
__global__ __launch_bounds__(512, 2) void gemm_qkv256(const u16* __restrict__ xb, const u16* __restrict__ wt,
                                                      const float* __restrict__ b0, const float* __restrict__ b1,
                                                      const float* __restrict__ b2,
                                                      u16* __restrict__ QKo, u16* __restrict__ VTo) {
  // LDS lives HERE (one copy shared by both template instantiations)
  __shared__ u16 lA[2][256 * 64];
  __shared__ u16 lB[2][256 * 64];
  const int z = blockIdx.z;
  const int swz = (blockIdx.x << 3) + blockIdx.y;   // 0..63
  const int mt = swz >> 2, nt = swz & 3;
  const u16* A = xb + (size_t)z * MR_ * K_;
  const u16* Bt = wt + (size_t)z * H_ * K_;
  if (z == 2) {
    body256<2>(A, Bt, b2, 1.0f, VTo, mt, nt, &lA[0][0], &lB[0][0]);
  } else {
    const float* bias = z == 0 ? b0 : b1;
    // fold 1/sqrt(HD) AND log2(e) into Q so softmax uses raw v_exp_f32 (exp2)
    const float scale = z == 0 ? 0.18033688011112042f : 1.0f;
    body256<0>(A, Bt, bias, scale, QKo + (size_t)z * MR_ * H_, mt, nt, &lA[0][0], &lB[0][0]);
  }
}

// ---------------- 128x128 GEMM body (proven) -- used by gemm_out only ----------------
__device__ __forceinline__ void gemm_body_f32(const u16* __restrict__ A, const u16* __restrict__ Bt,
                                              const float* __restrict__ bias, float* __restrict__ Of,
                                              int m_tile, int n_tile) {
  __shared__ u16 ldsA[128 * 64];
  __shared__ u16 ldsB[128 * 64];
  const int tid = threadIdx.x;
  const int lane = tid & 63, wave = tid >> 6;
  const int wm = wave >> 1, wn = wave & 1;
  const int m0 = m_tile * 128, n0 = n_tile * 128;

  f32x4 acc[4][4] = {};

  const int srow = tid >> 3;                     // 0..31
  const int sslot = (tid & 7) ^ (srow & 7);      // logical k-slot to fetch (pre-swizzled source)
  const u16* ga = A + (size_t)(m0 + srow) * K_ + sslot * 8;
  const u16* gb = Bt + (size_t)(n0 + srow) * K_ + sslot * 8;
  u16* la = ldsA + tid * 8;
  u16* lb = ldsB + tid * 8;

  const int fr = lane & 15;   // fragment row (A: m, B: n)
  const int kg = lane >> 4;   // k-group 0..3

  for (int k0 = 0; k0 < K_; k0 += 64) {
    #pragma unroll
    for (int j = 0; j < 4; j++) gload16(ga + (size_t)(j * 32) * K_ + k0, la + j * 2048);
    #pragma unroll
    for (int j = 0; j < 4; j++) gload16(gb + (size_t)(j * 32) * K_ + k0, lb + j * 2048);
    __syncthreads();

    #pragma unroll
    for (int kk = 0; kk < 2; kk++) {
      const int ps = (((kk << 2) | kg) ^ (fr & 7)) * 8;   // swizzled read
      bf16x8 a[4], b[4];
      #pragma unroll
      for (int mf = 0; mf < 4; mf++)
        a[mf] = *(const bf16x8*)&ldsA[(wm * 64 + mf * 16 + fr) * 64 + ps];
      #pragma unroll
      for (int nf = 0; nf < 4; nf++)
        b[nf] = *(const bf16x8*)&ldsB[(wn * 64 + nf * 16 + fr) * 64 + ps];
      #pragma unroll
      for (int mf = 0; mf < 4; mf++)
        #pragma unroll
        for (int nf = 0; nf < 4; nf++)
          acc[mf][nf] = __builtin_amdgcn_mfma_f32_16x16x32_bf16(a[mf], b[nf], acc[mf][nf], 0, 0, 0);
    }
    __syncthreads();
  }

  float bcol[4];
  #pragma unroll
  for (int nf = 0; nf < 4; nf++) bcol[nf] = bias[n0 + wn * 64 + nf * 16 + fr];
  #pragma unroll
  for (int mf = 0; mf < 4; mf++)
    #pragma unroll
    for (int r = 0; r < 4; r++) {
      const int row = m0 + wm * 64 + mf * 16 + kg * 4 + r;
      #pragma unroll
      for (int nf = 0; nf < 4; nf++) {
        const int col = n0 + wn * 64 + nf * 16 + fr;
        Of[(size_t)row * H_ + col] = acc[mf][nf][r] + bcol[nf];
      }
    }
}

__global__ __launch_bounds__(256) void gemm_out(const u16* __restrict__ ctx, const u16* __restrict__ wot,
                                                const float* __restrict__ bo, float* __restrict__ out) {
  const int bid = blockIdx.x + (blockIdx.y << 3);      // 0..255
  const int swz = ((bid & 7) << 5) + (bid >> 3);       // XCD-chunked
  gemm_body_f32(ctx, wot, bo, out, swz >> 3, swz & 7);
}

// ---------------- flash attention: 8 waves, in-block split-KV ----------------
__global__ __launch_bounds__(512, 4) void attn(const u16* __restrict__ qp, const u16* __restrict__ kp,
                                               const u16* __restrict__ vt, u16* __restrict__ ctx) {
  __shared__ u16 Kl[2][2][64 * 64];   // [group][buf][s][d-slot], phys_slot = slot ^ (s&7)
  __shared__ u16 Vl[2][2][64 * 64];   // [group][buf][d][s-slot], phys_slot = slot ^ (d&7)
  __shared__ float mlbuf[2][4][32][2];
  // XCD-chunked bijective swizzle: 16 q-tiles per bh stay on one XCD
  const int bid = blockIdx.x + (blockIdx.y << 4);
  const int swz = ((bid & 7) << 6) + (bid >> 3);
  const int bh = swz >> 4;
  const int b = bh >> 4, h = bh & 15;
  const int q0 = (swz & 15) * 128;
  const int tid = threadIdx.x;
  const int g0 = tid >> 8;            // kv-half group
  const int gt = tid & 255;           // thread id within group
  const int w = (tid >> 6) & 3;       // wave within group
  const int l = tid & 63;
  const int ql = l & 31, hi = l >> 5;

  const u16* Q   = qp + (size_t)b * S_ * H_ + h * HD_;
  const u16* Kb  = kp + (size_t)b * S_ * H_ + h * HD_;
  const u16* Vtb = vt + (size_t)bh * HD_ * S_;
  u16* O = ctx + (size_t)b * S_ * H_ + h * HD_;

  const int srow = gt >> 3;                   // 0..31
  const int sslot = (gt & 7) ^ (srow & 7);    // logical slot to fetch (pre-swizzled source)
  const int sbase = g0 << 10;                 // this group's kv offset

  // Q row base (fragments reloaded per iter; addresses loop-invariant, L1-resident)
  const u16* Qrow = Q + (size_t)(q0 + w * 32 + ql) * H_;

  f32x16 oacc0 = {}, oacc1 = {};       // C[q][d], dt=0,1 ; rows q=(r&3)+8*(r>>2)+4*hi, col d=dt*32+ql
  float m_run = -1e30f, l_run = 0.f;   // state for q-col = ql (mirrored on lane pair)

  // prologue: stage tile 0 into buffer 0
  #pragma unroll
  for (int j = 0; j < 2; j++) {
    gload16(Kb + (size_t)(sbase + srow + 32 * j) * H_ + sslot * 8,
            &Kl[g0][0][0] + j * 2048 + gt * 8);
    gload16(Vtb + (size_t)(srow + 32 * j) * S_ + sbase + sslot * 8,
            &Vl[g0][0][0] + j * 2048 + gt * 8);
  }

  for (int it = 0; it < 16; ++it) {
    const int s0 = sbase + it * 64, cur = it & 1;
    __syncthreads();   // staged tile visible
    if (it + 1 < 16) {
      #pragma unroll
      for (int j = 0; j < 2; j++) {
        gload16(Kb + (size_t)(s0 + 64 + srow + 32 * j) * H_ + sslot * 8,
                &Kl[g0][cur ^ 1][0] + j * 2048 + gt * 8);
        gload16(Vtb + (size_t)(srow + 32 * j) * S_ + s0 + 64 + sslot * 8,
                &Vl[g0][cur ^ 1][0] + j * 2048 + gt * 8);
      }
    }
    // swapped QK^T: sc_st = mfma32(K_frag, Q_frag). D[s][q]: q=l&31, s=st*32+(r&3)+8*(r>>2)+4*hi
    f32x16 sc0 = {}, sc1 = {};
    __builtin_amdgcn_s_setprio(1);
    #pragma unroll
    for (int ds = 0; ds < 4; ds++) {
      const int sl = ((ds * 2 + hi) ^ (ql & 7)) << 3;
      bf16x8 qd = *(const bf16x8*)&Qrow[ds * 16 + hi * 8];   // re-materialized (L1 hit)
      bf16x8 k0 = *(const bf16x8*)&Kl[g0][cur][ql * 64 + sl];
      bf16x8 k1 = *(const bf16x8*)&Kl[g0][cur][(32 + ql) * 64 + sl];
      sc0 = __builtin_amdgcn_mfma_f32_32x32x16_bf16(k0, qd, sc0, 0, 0, 0);
      sc1 = __builtin_amdgcn_mfma_f32_32x32x16_bf16(k1, qd, sc1, 0, 0, 0);
    }
    __builtin_amdgcn_s_setprio(0);
    // tree max over 32 in-register scores, then one cross-half reduce
    float t4[8];
    #pragma unroll
    for (int g = 0; g < 4; g++) {
      t4[g]     = fmaxf(fmaxf(sc0[4*g], sc0[4*g+1]), fmaxf(sc0[4*g+2], sc0[4*g+3]));
      t4[4 + g] = fmaxf(fmaxf(sc1[4*g], sc1[4*g+1]), fmaxf(sc1[4*g+2], sc1[4*g+3]));
    }
    float tmax = fmaxf(fmaxf(fmaxf(t4[0], t4[1]), fmaxf(t4[2], t4[3])),
                       fmaxf(fmaxf(t4[4], t4[5]), fmaxf(t4[6], t4[7])));
    tmax = fmaxf(tmax, __shfl_xor(tmax, 32, 64));
    // defer-max (THR=8 log2 units)
    if (!__all(tmax <= m_run + 8.0f)) {
      const float mn = fmaxf(m_run, tmax);
      const float sf = __builtin_amdgcn_exp2f(m_run - mn);
      m_run = mn;
      l_run *= sf;
      #pragma unroll
      for (int r = 0; r < 16; r++) {
        const float sfq = __shfl(sf, (r & 3) + 8 * (r >> 2) + 4 * hi, 64);
        oacc0[r] *= sfq;
        oacc1[r] *= sfq;
      }
    }
    // p = exp2(sc - m_run); psum; cvt_pk packs (pk[st][g] covers s' = 8g+4*hi+(0..3))
    float ps4[8];
    #pragma unroll
    for (int g = 0; g < 4; g++) {
      #pragma unroll
      for (int m = 0; m < 4; m++) {
        sc0[4*g+m] = __builtin_amdgcn_exp2f(sc0[4*g+m] - m_run);
        sc1[4*g+m] = __builtin_amdgcn_exp2f(sc1[4*g+m] - m_run);
      }
      ps4[g]     = (sc0[4*g] + sc0[4*g+1]) + (sc0[4*g+2] + sc0[4*g+3]);
      ps4[4 + g] = (sc1[4*g] + sc1[4*g+1]) + (sc1[4*g+2] + sc1[4*g+3]);
    }
    float psum = ((ps4[0] + ps4[1]) + (ps4[2] + ps4[3])) + ((ps4[4] + ps4[5]) + (ps4[6] + ps4[7]));
    psum += __shfl_xor(psum, 32, 64);
    l_run += psum;
    uint2 pk0[4], pk1[4];
    #pragma unroll
    for (int g = 0; g < 4; g++) {
      pk0[g].x = cvtpk(sc0[4*g], sc0[4*g+1]);  pk0[g].y = cvtpk(sc0[4*g+2], sc0[4*g+3]);
      pk1[g].x = cvtpk(sc1[4*g], sc1[4*g+1]);  pk1[g].y = cvtpk(sc1[4*g+2], sc1[4*g+3]);
    }
    // PV: A = P[q][s] assembled via permlane32_swap; B = V^T[d][s] from LDS
    __builtin_amdgcn_s_setprio(1);
    #pragma unroll
    for (int ks = 0; ks < 4; ks++) {
      const int ga = (ks & 1) * 2;
      unsigned x0, y0, x1, y1;
      if (ks < 2) { x0 = pk0[ga].x; y0 = pk0[ga].y; x1 = pk0[ga+1].x; y1 = pk0[ga+1].y; }
      else        { x0 = pk1[ga].x; y0 = pk1[ga].y; x1 = pk1[ga+1].x; y1 = pk1[ga+1].y; }
      plswap(x0, x1);   // x0 -> j0..1 merged, x1 -> j4..5
      plswap(y0, y1);   // y0 -> j2..3,        y1 -> j6..7
      u32x4 fu = { x0, y0, x1, y1 };
      const bf16x8 pfrag = __builtin_bit_cast(bf16x8, fu);
      #pragma unroll
      for (int dt = 0; dt < 2; dt++) {
        const int d = dt * 32 + ql;
        bf16x8 vf = *(const bf16x8*)&Vl[g0][cur][d * 64 + (((ks * 2 + hi) ^ (d & 7)) << 3)];
        if (dt == 0) oacc0 = __builtin_amdgcn_mfma_f32_32x32x16_bf16(pfrag, vf, oacc0, 0, 0, 0);
        else         oacc1 = __builtin_amdgcn_mfma_f32_32x32x16_bf16(pfrag, vf, oacc1, 0, 0, 0);
      }
    }
    __builtin_amdgcn_s_setprio(0);
  }

  // -------- merge the two kv-half partials --------
  if (l < 32) { mlbuf[g0][w][ql][0] = m_run; mlbuf[g0][w][ql][1] = l_run; }
  __syncthreads();   // ml visible; also: all LDS K/V reads done -> Kl reusable
  const float m_o = mlbuf[g0 ^ 1][w][ql][0];
  const float l_o = mlbuf[g0 ^ 1][w][ql][1];
  const float m_tot = fmaxf(m_run, m_o);
  const float a_s = __builtin_amdgcn_exp2f(m_run - m_tot);
  const float rinv = 1.0f / (l_run * a_s + l_o * __builtin_amdgcn_exp2f(m_o - m_tot));
  // broadcast BOTH a_s and rinv to the oacc row owners (row q=qi, NOT ql)
  float ar[16], rr[16];
  #pragma unroll
  for (int r = 0; r < 16; r++) {
    const int qi = (r & 3) + 8 * (r >> 2) + 4 * hi;
    ar[r] = __shfl(a_s, qi, 64);
    rr[r] = __shfl(rinv, qi, 64);
  }

  float* cb = (float*)(&Kl[0][0][0]);          // 32 KB scratch (retired K tiles)
  float* cw = cb + w * 2048 + l;
  if (g0 == 1) {
    #pragma unroll
    for (int r = 0; r < 16; r++) {
      cw[r * 64]        = oacc0[r] * ar[r];
      cw[(16 + r) * 64] = oacc1[r] * ar[r];
    }
  }
  __syncthreads();
  if (g0 == 0) {
    #pragma unroll
    for (int r = 0; r < 16; r++) {
      const int qi = (r & 3) + 8 * (r >> 2) + 4 * hi;
      const int row = q0 + w * 32 + qi;
      O[(size_t)row * H_ + ql]      = f2bf((oacc0[r] * ar[r] + cw[r * 64]) * rr[r]);
      O[(size_t)row * H_ + 32 + ql] = f2bf((oacc1[r] * ar[r] + cw[(16 + r) * 64]) * rr[r]);
    }
  }
}

extern "C" void kernel_launch(void* const* d_in, const int* in_sizes, int n_in,
                              void* d_out, int out_size, void* d_ws, size_t ws_size,
                              hipStream_t stream) {
  const float* q  = (const float*)d_in[0];
  const float* k  = (const float*)d_in[1];
  const float* v  = (const float*)d_in[2];
  const float* Wq = (const float*)d_in[3];
  const float* bq = (const float*)d_in[4];
  const float* Wk = (const float*)d_in[5];
  const float* bk = (const float*)d_in[6];
  const float* Wv = (const float*)d_in[7];
  const float* bv = (const float*)d_in[8];
  const float* Wo = (const float*)d_in[9];
  const float* bo = (const float*)d_in[10];
  float* out = (float*)d_out;

  char* ws = (char*)d_ws;
  const size_t MB = 1024 * 1024;
  u16* xb   = (u16*)(ws);             // q,k,v bf16: 3 x 8MB      [0,24)
  u16* wt   = (u16*)(ws + 24 * MB);   // 4 x 2MB transposed W     [24,32)
  u16* qkp  = (u16*)(ws + 32 * MB);   // qp,kp: 2 x 8MB           [32,48)
  u16* vtp  = (u16*)(ws + 48 * MB);   // V^T [bh][d][s]: 8MB      [48,56)
  u16* ctx  = (u16*)(ws);             // reuse xb region after gemm_qkv

  prep      <<<dim3(16384),     256, 0, stream>>>(q, k, v, Wq, Wk, Wv, Wo, xb, wt);
  gemm_qkv256<<<dim3(8, 8, 3),  512, 0, stream>>>(xb, wt, bq, bk, bv, qkp, vtp);
  attn      <<<dim3(16, 32),    512, 0, stream>>>(qkp, qkp + (size_t)MR_ * H_, vtp, ctx);
  gemm_out  <<<dim3(8, 32, 1),  256, 0, stream>>>(ctx, wt + (size_t)3 * H_ * K_, bo, out);
}

// Round 17
// 130.413 us; speedup vs baseline: 1.0522x; 1.0067x over previous
//
#include <hip/hip_runtime.h>

typedef unsigned short u16;
typedef __attribute__((ext_vector_type(8))) short bf16x8;
typedef __attribute__((ext_vector_type(4))) float f32x4;
typedef __attribute__((ext_vector_type(16))) float f32x16;
typedef __attribute__((ext_vector_type(4))) unsigned short u16x4;
typedef __attribute__((ext_vector_type(4))) unsigned int u32x4;

#define B_  2
#define S_  2048
#define H_  1024
#define NH_ 16
#define HD_ 64
#define MR_ (B_*S_)   /* 4096 rows */
#define K_  H_

__device__ __forceinline__ u16 f2bf(float f) {
  union { float f; unsigned u; } x; x.f = f;
  unsigned r = x.u + 0x7fffu + ((x.u >> 16) & 1u);
  return (u16)(r >> 16);
}

// packed f32x2 -> bf16x2 (RNE), single VALU op (no builtin on gfx950)
__device__ __forceinline__ unsigned cvtpk(float lo, float hi) {
  unsigned r;
  asm("v_cvt_pk_bf16_f32 %0, %1, %2" : "=v"(r) : "v"(lo), "v"(hi));
  return r;
}

// v_permlane32_swap_b32: a' = [a.lo32lanes | b.lo32lanes], b' = [a.hi32lanes | b.hi32lanes]
__device__ __forceinline__ void plswap(unsigned &a, unsigned &b) {
  asm("v_permlane32_swap_b32 %0, %1" : "+v"(a), "+v"(b));
}

__device__ __forceinline__ void gload16(const u16* g, u16* l) {
  __builtin_amdgcn_global_load_lds((const __attribute__((address_space(1))) void*)g,
                                   (__attribute__((address_space(3))) void*)l, 16, 0, 0);
}

// ---------------- prep: cvt q,k,v f32->bf16 (blocks 0..12287) + W transpose (12288..16383) ----------------
__global__ __launch_bounds__(256) void prep(const float* __restrict__ q, const float* __restrict__ k,
                                            const float* __restrict__ v, const float* __restrict__ Wq,
                                            const float* __restrict__ Wk, const float* __restrict__ Wv,
                                            const float* __restrict__ Wo, u16* __restrict__ dst,
                                            u16* __restrict__ wt) {
  __shared__ float t[32][33];
  const int bid = blockIdx.x;
  if (bid < 12288) {
    const int z = bid >> 12;
    const float* src = z == 0 ? q : z == 1 ? k : v;
    u16* d = dst + (size_t)z * MR_ * H_;
    size_t i = ((size_t)(bid & 4095) * 256 + threadIdx.x) * 4;
    float4 f = *(const float4*)(src + i);
    u16x4 o = { f2bf(f.x), f2bf(f.y), f2bf(f.z), f2bf(f.w) };
    *(u16x4*)(d + i) = o;
  } else {
    const int r = bid - 12288;
    const int z = r >> 10;
    const float* W = z == 0 ? Wq : z == 1 ? Wk : z == 2 ? Wv : Wo;
    u16* Wt = wt + (size_t)z * H_ * K_;
    const int n0 = (r & 31) * 32, k0 = ((r >> 5) & 31) * 32;
    const int tx = threadIdx.x & 31, ty = threadIdx.x >> 5;  // ty 0..7
    #pragma unroll
    for (int i = 0; i < 4; i++) t[ty + 8*i][tx] = W[(size_t)(k0 + ty + 8*i) * H_ + n0 + tx];
    __syncthreads();
    #pragma unroll
    for (int i = 0; i < 4; i++) Wt[(size_t)(n0 + ty + 8*i) * K_ + k0 + tx] = f2bf(t[tx][ty + 8*i]);
  }
}

// ============ 256x256 phase-interleaved GEMM (T3-style) for QKV ============
template <int MODE>
__device__ __forceinline__ void body256(const u16* __restrict__ A, const u16* __restrict__ Bt,
                                        const float* __restrict__ bias, float scale,
                                        u16* __restrict__ Obf, int mt, int nt,
                                        u16* lAbase, u16* lBbase) {
  const int tid = threadIdx.x;
  const int lane = tid & 63, wave = tid >> 6;
  const int wm = wave >> 2, wn = wave & 3;
  const int fr = lane & 15, kg = lane >> 4;
  const int m0 = mt * 256, n0 = nt * 256;

  const int srow = tid >> 3;                   // 0..63
  const int sslot = (tid & 7) ^ (srow & 7);    // logical slot to fetch (pre-swizzled source)
  const u16* ga = A + (size_t)(m0 + srow) * K_ + sslot * 8;
  const u16* gb = Bt + (size_t)(n0 + srow) * K_ + sslot * 8;

  f32x4 acc[8][4] = {};

  // prologue: stage step 0 into buf 0
  #pragma unroll
  for (int j = 0; j < 4; j++) {
    gload16(ga + (size_t)(j * 64) * K_, lAbase + j * 4096 + tid * 8);
    gload16(gb + (size_t)(j * 64) * K_, lBbase + j * 4096 + tid * 8);
  }
  asm volatile("s_waitcnt vmcnt(0)" ::: "memory");
  __builtin_amdgcn_s_barrier();
  __builtin_amdgcn_sched_barrier(0);

  for (int s = 0; s < 16; ++s) {
    const int cur = s & 1;
    const u16* Acur = lAbase + cur * 16384;
    const u16* Bcur = lBbase + cur * 16384;
    u16* Anxt = lAbase + (cur ^ 1) * 16384;
    u16* Bnxt = lBbase + (cur ^ 1) * 16384;
    const size_t knext = (size_t)(s + 1) * 64;
    bf16x8 af[4][2];
    #pragma unroll
    for (int p = 0; p < 4; ++p) {
      const int mh = p >> 1, nh = p & 1;
      if ((p & 1) == 0) {   // new A-half (kept across 2 phases)
        #pragma unroll
        for (int mf2 = 0; mf2 < 4; ++mf2)
          #pragma unroll
          for (int kk = 0; kk < 2; ++kk)
            af[mf2][kk] = *(const bf16x8*)&Acur[(wm * 128 + mh * 64 + mf2 * 16 + fr) * 64 +
                                                ((((kk << 2) | kg) ^ (fr & 7)) << 3)];
      }
      bf16x8 bfr[2][2];
      #pragma unroll
      for (int nf2 = 0; nf2 < 2; ++nf2)
        #pragma unroll
        for (int kk = 0; kk < 2; ++kk)
          bfr[nf2][kk] = *(const bf16x8*)&Bcur[(wn * 64 + nh * 32 + nf2 * 16 + fr) * 64 +
                                               ((((kk << 2) | kg) ^ (fr & 7)) << 3)];
      if (s < 15 && p < 2) {   // front-load next-step staging (phases 0,1)
        #pragma unroll
        for (int jj = 0; jj < 2; ++jj) {
          const int j = p * 2 + jj;
          gload16(ga + (size_t)(j * 64) * K_ + knext, Anxt + j * 4096 + tid * 8);
          gload16(gb + (size_t)(j * 64) * K_ + knext, Bnxt + j * 4096 + tid * 8);
        }
      }
      __builtin_amdgcn_s_barrier();          // align waves entering MFMA cluster
      __builtin_amdgcn_s_setprio(1);
      #pragma unroll
      for (int mf2 = 0; mf2 < 4; ++mf2)
        #pragma unroll
        for (int nf2 = 0; nf2 < 2; ++nf2)
          #pragma unroll
          for (int kk = 0; kk < 2; ++kk)
            acc[mh * 4 + mf2][nh * 2 + nf2] = __builtin_amdgcn_mfma_f32_16x16x32_bf16(
                af[mf2][kk], bfr[nf2][kk], acc[mh * 4 + mf2][nh * 2 + nf2], 0, 0, 0);
      __builtin_amdgcn_s_setprio(0);
      if (p < 3) {
        __builtin_amdgcn_s_barrier();
      } else {
        asm volatile("s_waitcnt vmcnt(0)" ::: "memory");
        __builtin_amdgcn_s_barrier();
        __builtin_amdgcn_sched_barrier(0);
      }
    }
  }

  float bcol[4];
  #pragma unroll
  for (int nf = 0; nf < 4; nf++) bcol[nf] = bias[n0 + wn * 64 + nf * 16 + fr];

  if (MODE == 2) {
    // V^T store: out[((b*16+h)*64+d)*2048 + s], col=h*64+d, row=b*2048+s.
    #pragma unroll
    for (int mf = 0; mf < 8; mf++) {
      const int row0 = m0 + wm * 128 + mf * 16 + kg * 4;
      #pragma unroll
      for (int nf = 0; nf < 4; nf++) {
        const int col = n0 + wn * 64 + nf * 16 + fr;
        u16x4 o;
        #pragma unroll
        for (int r = 0; r < 4; r++) o[r] = f2bf(acc[mf][nf][r] + bcol[nf]);
        size_t idx = (((size_t)(col + ((row0 >> 11) << 10))) << 11) + (row0 & 2047);
        *(u16x4*)(Obf + idx) = o;
      }
    }
  } else {
    #pragma unroll
    for (int mf = 0; mf < 8; mf++)
      #pragma unroll
      for (int r = 0; r < 4; r++) {
        const int row = m0 + wm * 128 + mf * 16 + kg * 4 + r;
        #pragma unroll
        for (int nf = 0; nf < 4; nf++) {
          const int col = n0 + wn * 64 + nf * 16 + fr;
          Obf[(size_t)row * H_ + col] = f2bf((acc[mf][nf][r] + bcol[nf]) * scale);
        }
      }
  }
}

// grid (8,8,3): xcd = blockIdx.x (64 blocks/plane, 8|64); XCD x owns m_tiles [2x,2x+2)
__global__ __launch_bounds__(512, 2) void gemm_qkv256(const u16* __restrict__ xb, const u16* __restrict__ wt,
                                                      const float* __restrict__ b0, const float* __restrict__ b1,
                                                      const float* __restrict__ b2,
                                                      u16* __restrict__ QKo, u16* __restrict__ VTo) {
  // LDS lives HERE (one copy shared by both template instantiations)
  __shared__ u16 lA[2][256 * 64];
  __shared__ u16 lB[2][256 * 64];
  const int z = blockIdx.z;
  const int swz = (blockIdx.x << 3) + blockIdx.y;   // 0..63
  const int mt = swz >> 2, nt = swz & 3;
  const u16* A = xb + (size_t)z * MR_ * K_;
  const u16* Bt = wt + (size_t)z * H_ * K_;
  if (z == 2) {
    body256<2>(A, Bt, b2, 1.0f, VTo, mt, nt, &lA[0][0], &lB[0][0]);
  } else {
    const float* bias = z == 0 ? b0 : b1;
    // fold 1/sqrt(HD) AND log2(e) into Q so softmax uses raw v_exp_f32 (exp2)
    const float scale = z == 0 ? 0.18033688011112042f : 1.0f;
    body256<0>(A, Bt, bias, scale, QKo + (size_t)z * MR_ * H_, mt, nt, &lA[0][0], &lB[0][0]);
  }
}

// ---------------- 128x128 GEMM body (proven) -- used by gemm_out only ----------------
__device__ __forceinline__ void gemm_body_f32(const u16* __restrict__ A, const u16* __restrict__ Bt,
                                              const float* __restrict__ bias, float* __restrict__ Of,
                                              int m_tile, int n_tile) {
  __shared__ u16 ldsA[128 * 64];
  __shared__ u16 ldsB[128 * 64];
  const int tid = threadIdx.x;
  const int lane = tid & 63, wave = tid >> 6;
  const int wm = wave >> 1, wn = wave & 1;
  const int m0 = m_tile * 128, n0 = n_tile * 128;

  f32x4 acc[4][4] = {};

  const int srow = tid >> 3;                     // 0..31
  const int sslot = (tid & 7) ^ (srow & 7);      // logical k-slot to fetch (pre-swizzled source)
  const u16* ga = A + (size_t)(m0 + srow) * K_ + sslot * 8;
  const u16* gb = Bt + (size_t)(n0 + srow) * K_ + sslot * 8;
  u16* la = ldsA + tid * 8;
  u16* lb = ldsB + tid * 8;

  const int fr = lane & 15;   // fragment row (A: m, B: n)
  const int kg = lane >> 4;   // k-group 0..3

  for (int k0 = 0; k0 < K_; k0 += 64) {
    #pragma unroll
    for (int j = 0; j < 4; j++) gload16(ga + (size_t)(j * 32) * K_ + k0, la + j * 2048);
    #pragma unroll
    for (int j = 0; j < 4; j++) gload16(gb + (size_t)(j * 32) * K_ + k0, lb + j * 2048);
    __syncthreads();

    #pragma unroll
    for (int kk = 0; kk < 2; kk++) {
      const int ps = (((kk << 2) | kg) ^ (fr & 7)) * 8;   // swizzled read
      bf16x8 a[4], b[4];
      #pragma unroll
      for (int mf = 0; mf < 4; mf++)
        a[mf] = *(const bf16x8*)&ldsA[(wm * 64 + mf * 16 + fr) * 64 + ps];
      #pragma unroll
      for (int nf = 0; nf < 4; nf++)
        b[nf] = *(const bf16x8*)&ldsB[(wn * 64 + nf * 16 + fr) * 64 + ps];
      #pragma unroll
      for (int mf = 0; mf < 4; mf++)
        #pragma unroll
        for (int nf = 0; nf < 4; nf++)
          acc[mf][nf] = __builtin_amdgcn_mfma_f32_16x16x32_bf16(a[mf], b[nf], acc[mf][nf], 0, 0, 0);
    }
    __syncthreads();
  }

  float bcol[4];
  #pragma unroll
  for (int nf = 0; nf < 4; nf++) bcol[nf] = bias[n0 + wn * 64 + nf * 16 + fr];
  #pragma unroll
  for (int mf = 0; mf < 4; mf++)
    #pragma unroll
    for (int r = 0; r < 4; r++) {
      const int row = m0 + wm * 64 + mf * 16 + kg * 4 + r;
      #pragma unroll
      for (int nf = 0; nf < 4; nf++) {
        const int col = n0 + wn * 64 + nf * 16 + fr;
        Of[(size_t)row * H_ + col] = acc[mf][nf][r] + bcol[nf];
      }
    }
}

__global__ __launch_bounds__(256) void gemm_out(const u16* __restrict__ ctx, const u16* __restrict__ wot,
                                                const float* __restrict__ bo, float* __restrict__ out) {
  const int bid = blockIdx.x + (blockIdx.y << 3);      // 0..255
  const int swz = ((bid & 7) << 5) + (bid >> 3);       // XCD-chunked
  gemm_body_f32(ctx, wot, bo, out, swz >> 3, swz & 7);
}

// ---------------- flash attention: 8 waves, in-block split-KV ----------------
// Q fragments hoisted back to persistent registers: VGPR was 64 at (512,4) -- 64 regs
// of headroom under the 128 budget. Removes 4 VMEM loads + waitcnts per iter from the
// QK^T critical path; launch bound still pins occupancy at 4 waves/EU.
__global__ __launch_bounds__(512, 4) void attn(const u16* __restrict__ qp, const u16* __restrict__ kp,
                                               const u16* __restrict__ vt, u16* __restrict__ ctx) {
  __shared__ u16 Kl[2][2][64 * 64];   // [group][buf][s][d-slot], phys_slot = slot ^ (s&7)
  __shared__ u16 Vl[2][2][64 * 64];   // [group][buf][d][s-slot], phys_slot = slot ^ (d&7)
  __shared__ float mlbuf[2][4][32][2];
  // XCD-chunked bijective swizzle: 16 q-tiles per bh stay on one XCD
  const int bid = blockIdx.x + (blockIdx.y << 4);
  const int swz = ((bid & 7) << 6) + (bid >> 3);
  const int bh = swz >> 4;
  const int b = bh >> 4, h = bh & 15;
  const int q0 = (swz & 15) * 128;
  const int tid = threadIdx.x;
  const int g0 = tid >> 8;            // kv-half group
  const int gt = tid & 255;           // thread id within group
  const int w = (tid >> 6) & 3;       // wave within group
  const int l = tid & 63;
  const int ql = l & 31, hi = l >> 5;

  const u16* Q   = qp + (size_t)b * S_ * H_ + h * HD_;
  const u16* Kb  = kp + (size_t)b * S_ * H_ + h * HD_;
  const u16* Vtb = vt + (size_t)bh * HD_ * S_;
  u16* O = ctx + (size_t)b * S_ * H_ + h * HD_;

  const int srow = gt >> 3;                   // 0..31
  const int sslot = (gt & 7) ^ (srow & 7);    // logical slot to fetch (pre-swizzled source)
  const int sbase = g0 << 10;                 // this group's kv offset

  // Q fragments hoisted (loop-invariant): lane holds Q[q=q0+w*32+ql][d=ds*16+hi*8+j]
  const u16* Qrow = Q + (size_t)(q0 + w * 32 + ql) * H_;
  bf16x8 qf[4];
  #pragma unroll
  for (int ds = 0; ds < 4; ds++)
    qf[ds] = *(const bf16x8*)&Qrow[ds * 16 + hi * 8];

  f32x16 oacc0 = {}, oacc1 = {};       // C[q][d], dt=0,1 ; rows q=(r&3)+8*(r>>2)+4*hi, col d=dt*32+ql
  float m_run = -1e30f, l_run = 0.f;   // state for q-col = ql (mirrored on lane pair)

  // prologue: stage tile 0 into buffer 0
  #pragma unroll
  for (int j = 0; j < 2; j++) {
    gload16(Kb + (size_t)(sbase + srow + 32 * j) * H_ + sslot * 8,
            &Kl[g0][0][0] + j * 2048 + gt * 8);
    gload16(Vtb + (size_t)(srow + 32 * j) * S_ + sbase + sslot * 8,
            &Vl[g0][0][0] + j * 2048 + gt * 8);
  }

  for (int it = 0; it < 16; ++it) {
    const int s0 = sbase + it * 64, cur = it & 1;
    __syncthreads();   // staged tile visible
    if (it + 1 < 16) {
      #pragma unroll
      for (int j = 0; j < 2; j++) {
        gload16(Kb + (size_t)(s0 + 64 + srow + 32 * j) * H_ + sslot * 8,
                &Kl[g0][cur ^ 1][0] + j * 2048 + gt * 8);
        gload16(Vtb + (size_t)(srow + 32 * j) * S_ + s0 + 64 + sslot * 8,
                &Vl[g0][cur ^ 1][0] + j * 2048 + gt * 8);
      }
    }
    // swapped QK^T: sc_st = mfma32(K_frag, Q_frag). D[s][q]: q=l&31, s=st*32+(r&3)+8*(r>>2)+4*hi
    f32x16 sc0 = {}, sc1 = {};
    __builtin_amdgcn_s_setprio(1);
    #pragma unroll
    for (int ds = 0; ds < 4; ds++) {
      const int sl = ((ds * 2 + hi) ^ (ql & 7)) << 3;
      bf16x8 k0 = *(const bf16x8*)&Kl[g0][cur][ql * 64 + sl];
      bf16x8 k1 = *(const bf16x8*)&Kl[g0][cur][(32 + ql) * 64 + sl];
      sc0 = __builtin_amdgcn_mfma_f32_32x32x16_bf16(k0, qf[ds], sc0, 0, 0, 0);
      sc1 = __builtin_amdgcn_mfma_f32_32x32x16_bf16(k1, qf[ds], sc1, 0, 0, 0);
    }
    __builtin_amdgcn_s_setprio(0);
    // tree max over 32 in-register scores, then one cross-half reduce
    float t4[8];
    #pragma unroll
    for (int g = 0; g < 4; g++) {
      t4[g]     = fmaxf(fmaxf(sc0[4*g], sc0[4*g+1]), fmaxf(sc0[4*g+2], sc0[4*g+3]));
      t4[4 + g] = fmaxf(fmaxf(sc1[4*g], sc1[4*g+1]), fmaxf(sc1[4*g+2], sc1[4*g+3]));
    }
    float tmax = fmaxf(fmaxf(fmaxf(t4[0], t4[1]), fmaxf(t4[2], t4[3])),
                       fmaxf(fmaxf(t4[4], t4[5]), fmaxf(t4[6], t4[7])));
    tmax = fmaxf(tmax, __shfl_xor(tmax, 32, 64));
    // defer-max (THR=8 log2 units)
    if (!__all(tmax <= m_run + 8.0f)) {
      const float mn = fmaxf(m_run, tmax);
      const float sf = __builtin_amdgcn_exp2f(m_run - mn);
      m_run = mn;
      l_run *= sf;
      #pragma unroll
      for (int r = 0; r < 16; r++) {
        const float sfq = __shfl(sf, (r & 3) + 8 * (r >> 2) + 4 * hi, 64);
        oacc0[r] *= sfq;
        oacc1[r] *= sfq;
      }
    }
    // p = exp2(sc - m_run); psum; cvt_pk packs (pk[st][g] covers s' = 8g+4*hi+(0..3))
    float ps4[8];
    #pragma unroll
    for (int g = 0; g < 4; g++) {
      #pragma unroll
      for (int m = 0; m < 4; m++) {
        sc0[4*g+m] = __builtin_amdgcn_exp2f(sc0[4*g+m] - m_run);
        sc1[4*g+m] = __builtin_amdgcn_exp2f(sc1[4*g+m] - m_run);
      }
      ps4[g]     = (sc0[4*g] + sc0[4*g+1]) + (sc0[4*g+2] + sc0[4*g+3]);
      ps4[4 + g] = (sc1[4*g] + sc1[4*g+1]) + (sc1[4*g+2] + sc1[4*g+3]);
    }
    float psum = ((ps4[0] + ps4[1]) + (ps4[2] + ps4[3])) + ((ps4[4] + ps4[5]) + (ps4[6] + ps4[7]));
    psum += __shfl_xor(psum, 32, 64);
    l_run += psum;
    uint2 pk0[4], pk1[4];
    #pragma unroll
    for (int g = 0; g < 4; g++) {
      pk0[g].x = cvtpk(sc0[4*g], sc0[4*g+1]);  pk0[g].y = cvtpk(sc0[4*g+2], sc0[4*g+3]);
      pk1[g].x = cvtpk(sc1[4*g], sc1[4*g+1]);  pk1[g].y = cvtpk(sc1[4*g+2], sc1[4*g+3]);
    }
    // PV: A = P[q][s] assembled via permlane32_swap; B = V^T[d][s] from LDS
    __builtin_amdgcn_s_setprio(1);
    #pragma unroll
    for (int ks = 0; ks < 4; ks++) {
      const int ga = (ks & 1) * 2;
      unsigned x0, y0, x1, y1;
      if (ks < 2) { x0 = pk0[ga].x; y0 = pk0[ga].y; x1 = pk0[ga+1].x; y1 = pk0[ga+1].y; }
      else        { x0 = pk1[ga].x; y0 = pk1[ga].y; x1 = pk1[ga+1].x; y1 = pk1[ga+1].y; }
      plswap(x0, x1);   // x0 -> j0..1 merged, x1 -> j4..5
      plswap(y0, y1);   // y0 -> j2..3,        y1 -> j6..7
      u32x4 fu = { x0, y0, x1, y1 };
      const bf16x8 pfrag = __builtin_bit_cast(bf16x8, fu);
      #pragma unroll
      for (int dt = 0; dt < 2; dt++) {
        const int d = dt * 32 + ql;
        bf16x8 vf = *(const bf16x8*)&Vl[g0][cur][d * 64 + (((ks * 2 + hi) ^ (d & 7)) << 3)];
        if (dt == 0) oacc0 = __builtin_amdgcn_mfma_f32_32x32x16_bf16(pfrag, vf, oacc0, 0, 0, 0);
        else         oacc1 = __builtin_amdgcn_mfma_f32_32x32x16_bf16(pfrag, vf, oacc1, 0, 0, 0);
      }
    }
    __builtin_amdgcn_s_setprio(0);
  }

  // -------- merge the two kv-half partials --------
  if (l < 32) { mlbuf[g0][w][ql][0] = m_run; mlbuf[g0][w][ql][1] = l_run; }
  __syncthreads();   // ml visible; also: all LDS K/V reads done -> Kl reusable
  const float m_o = mlbuf[g0 ^ 1][w][ql][0];
  const float l_o = mlbuf[g0 ^ 1][w][ql][1];
  const float m_tot = fmaxf(m_run, m_o);
  const float a_s = __builtin_amdgcn_exp2f(m_run - m_tot);
  const float rinv = 1.0f / (l_run * a_s + l_o * __builtin_amdgcn_exp2f(m_o - m_tot));
  // broadcast BOTH a_s and rinv to the oacc row owners (row q=qi, NOT ql)
  float ar[16], rr[16];
  #pragma unroll
  for (int r = 0; r < 16; r++) {
    const int qi = (r & 3) + 8 * (r >> 2) + 4 * hi;
    ar[r] = __shfl(a_s, qi, 64);
    rr[r] = __shfl(rinv, qi, 64);
  }

  float* cb = (float*)(&Kl[0][0][0]);          // 32 KB scratch (retired K tiles)
  float* cw = cb + w * 2048 + l;
  if (g0 == 1) {
    #pragma unroll
    for (int r = 0; r < 16; r++) {
      cw[r * 64]        = oacc0[r] * ar[r];
      cw[(16 + r) * 64] = oacc1[r] * ar[r];
    }
  }
  __syncthreads();
  if (g0 == 0) {
    #pragma unroll
    for (int r = 0; r < 16; r++) {
      const int qi = (r & 3) + 8 * (r >> 2) + 4 * hi;
      const int row = q0 + w * 32 + qi;
      O[(size_t)row * H_ + ql]      = f2bf((oacc0[r] * ar[r] + cw[r * 64]) * rr[r]);
      O[(size_t)row * H_ + 32 + ql] = f2bf((oacc1[r] * ar[r] + cw[(16 + r) * 64]) * rr[r]);
    }
  }
}

extern "C" void kernel_launch(void* const* d_in, const int* in_sizes, int n_in,
                              void* d_out, int out_size, void* d_ws, size_t ws_size,
                              hipStream_t stream) {
  const float* q  = (const float*)d_in[0];
  const float* k  = (const float*)d_in[1];
  const float* v  = (const float*)d_in[2];
  const float* Wq = (const float*)d_in[3];
  const float* bq = (const float*)d_in[4];
  const float* Wk = (const float*)d_in[5];
  const float* bk = (const float*)d_in[6];
  const float* Wv = (const float*)d_in[7];
  const float* bv = (const float*)d_in[8];
  const float* Wo = (const float*)d_in[9];
  const float* bo = (const float*)d_in[10];
  float* out = (float*)d_out;

  char* ws = (char*)d_ws;
  const size_t MB = 1024 * 1024;
  u16* xb   = (u16*)(ws);             // q,k,v bf16: 3 x 8MB      [0,24)
  u16* wt   = (u16*)(ws + 24 * MB);   // 4 x 2MB transposed W     [24,32)
  u16* qkp  = (u16*)(ws + 32 * MB);   // qp,kp: 2 x 8MB           [32,48)
  u16* vtp  = (u16*)(ws + 48 * MB);   // V^T [bh][d][s]: 8MB      [48,56)
  u16* ctx  = (u16*)(ws);             // reuse xb region after gemm_qkv

  prep      <<<dim3(16384),     256, 0, stream>>>(q, k, v, Wq, Wk, Wv, Wo, xb, wt);
  gemm_qkv256<<<dim3(8, 8, 3),  512, 0, stream>>>(xb, wt, bq, bk, bv, qkp, vtp);
  attn      <<<dim3(16, 32),    512, 0, stream>>>(qkp, qkp + (size_t)MR_ * H_, vtp, ctx);
  gemm_out  <<<dim3(8, 32, 1),  256, 0, stream>>>(ctx, wt + (size_t)3 * H_ * K_, bo, out);
}

// Round 18
// 130.054 us; speedup vs baseline: 1.0551x; 1.0028x over previous
//
#include <hip/hip_runtime.h>

typedef unsigned short u16;
typedef __attribute__((ext_vector_type(8))) short bf16x8;
typedef __attribute__((ext_vector_type(4))) float f32x4;
typedef __attribute__((ext_vector_type(16))) float f32x16;
typedef __attribute__((ext_vector_type(4))) unsigned short u16x4;
typedef __attribute__((ext_vector_type(4))) unsigned int u32x4;

#define B_  2
#define S_  2048
#define H_  1024
#define NH_ 16
#define HD_ 64
#define MR_ (B_*S_)   /* 4096 rows */
#define K_  H_

__device__ __forceinline__ u16 f2bf(float f) {
  union { float f; unsigned u; } x; x.f = f;
  unsigned r = x.u + 0x7fffu + ((x.u >> 16) & 1u);
  return (u16)(r >> 16);
}

// packed f32x2 -> bf16x2 (RNE), single VALU op (no builtin on gfx950)
__device__ __forceinline__ unsigned cvtpk(float lo, float hi) {
  unsigned r;
  asm("v_cvt_pk_bf16_f32 %0, %1, %2" : "=v"(r) : "v"(lo), "v"(hi));
  return r;
}

// v_permlane32_swap_b32: a' = [a.lo32lanes | b.lo32lanes], b' = [a.hi32lanes | b.hi32lanes]
__device__ __forceinline__ void plswap(unsigned &a, unsigned &b) {
  asm("v_permlane32_swap_b32 %0, %1" : "+v"(a), "+v"(b));
}

__device__ __forceinline__ void gload16(const u16* g, u16* l) {
  __builtin_amdgcn_global_load_lds((const __attribute__((address_space(1))) void*)g,
                                   (__attribute__((address_space(3))) void*)l, 16, 0, 0);
}

// ---------------- prep: cvt q,k,v f32->bf16 (blocks 0..12287) + W transpose (12288..16383) ----------------
__global__ __launch_bounds__(256) void prep(const float* __restrict__ q, const float* __restrict__ k,
                                            const float* __restrict__ v, const float* __restrict__ Wq,
                                            const float* __restrict__ Wk, const float* __restrict__ Wv,
                                            const float* __restrict__ Wo, u16* __restrict__ dst,
                                            u16* __restrict__ wt) {
  __shared__ float t[32][33];
  const int bid = blockIdx.x;
  if (bid < 12288) {
    const int z = bid >> 12;
    const float* src = z == 0 ? q : z == 1 ? k : v;
    u16* d = dst + (size_t)z * MR_ * H_;
    size_t i = ((size_t)(bid & 4095) * 256 + threadIdx.x) * 4;
    float4 f = *(const float4*)(src + i);
    u16x4 o = { f2bf(f.x), f2bf(f.y), f2bf(f.z), f2bf(f.w) };
    *(u16x4*)(d + i) = o;
  } else {
    const int r = bid - 12288;
    const int z = r >> 10;
    const float* W = z == 0 ? Wq : z == 1 ? Wk : z == 2 ? Wv : Wo;
    u16* Wt = wt + (size_t)z * H_ * K_;
    const int n0 = (r & 31) * 32, k0 = ((r >> 5) & 31) * 32;
    const int tx = threadIdx.x & 31, ty = threadIdx.x >> 5;  // ty 0..7
    #pragma unroll
    for (int i = 0; i < 4; i++) t[ty + 8*i][tx] = W[(size_t)(k0 + ty + 8*i) * H_ + n0 + tx];
    __syncthreads();
    #pragma unroll
    for (int i = 0; i < 4; i++) Wt[(size_t)(n0 + ty + 8*i) * K_ + k0 + tx] = f2bf(t[tx][ty + 8*i]);
  }
}

// ============ 256x256 phase-interleaved GEMM (T3-style) for QKV ============
template <int MODE>
__device__ __forceinline__ void body256(const u16* __restrict__ A, const u16* __restrict__ Bt,
                                        const float* __restrict__ bias, float scale,
                                        u16* __restrict__ Obf, int mt, int nt,
                                        u16* lAbase, u16* lBbase) {
  const int tid = threadIdx.x;
  const int lane = tid & 63, wave = tid >> 6;
  const int wm = wave >> 2, wn = wave & 3;
  const int fr = lane & 15, kg = lane >> 4;
  const int m0 = mt * 256, n0 = nt * 256;

  const int srow = tid >> 3;                   // 0..63
  const int sslot = (tid & 7) ^ (srow & 7);    // logical slot to fetch (pre-swizzled source)
  const u16* ga = A + (size_t)(m0 + srow) * K_ + sslot * 8;
  const u16* gb = Bt + (size_t)(n0 + srow) * K_ + sslot * 8;

  f32x4 acc[8][4] = {};

  // prologue: stage step 0 into buf 0
  #pragma unroll
  for (int j = 0; j < 4; j++) {
    gload16(ga + (size_t)(j * 64) * K_, lAbase + j * 4096 + tid * 8);
    gload16(gb + (size_t)(j * 64) * K_, lBbase + j * 4096 + tid * 8);
  }
  asm volatile("s_waitcnt vmcnt(0)" ::: "memory");
  __builtin_amdgcn_s_barrier();
  __builtin_amdgcn_sched_barrier(0);

  for (int s = 0; s < 16; ++s) {
    const int cur = s & 1;
    const u16* Acur = lAbase + cur * 16384;
    const u16* Bcur = lBbase + cur * 16384;
    u16* Anxt = lAbase + (cur ^ 1) * 16384;
    u16* Bnxt = lBbase + (cur ^ 1) * 16384;
    const size_t knext = (size_t)(s + 1) * 64;
    bf16x8 af[4][2];
    #pragma unroll
    for (int p = 0; p < 4; ++p) {
      const int mh = p >> 1, nh = p & 1;
      if ((p & 1) == 0) {   // new A-half (kept across 2 phases)
        #pragma unroll
        for (int mf2 = 0; mf2 < 4; ++mf2)
          #pragma unroll
          for (int kk = 0; kk < 2; ++kk)
            af[mf2][kk] = *(const bf16x8*)&Acur[(wm * 128 + mh * 64 + mf2 * 16 + fr) * 64 +
                                                ((((kk << 2) | kg) ^ (fr & 7)) << 3)];
      }
      bf16x8 bfr[2][2];
      #pragma unroll
      for (int nf2 = 0; nf2 < 2; ++nf2)
        #pragma unroll
        for (int kk = 0; kk < 2; ++kk)
          bfr[nf2][kk] = *(const bf16x8*)&Bcur[(wn * 64 + nh * 32 + nf2 * 16 + fr) * 64 +
                                               ((((kk << 2) | kg) ^ (fr & 7)) << 3)];
      if (s < 15 && p < 2) {   // front-load next-step staging (phases 0,1)
        #pragma unroll
        for (int jj = 0; jj < 2; ++jj) {
          const int j = p * 2 + jj;
          gload16(ga + (size_t)(j * 64) * K_ + knext, Anxt + j * 4096 + tid * 8);
          gload16(gb + (size_t)(j * 64) * K_ + knext, Bnxt + j * 4096 + tid * 8);
        }
      }
      __builtin_amdgcn_s_barrier();          // align waves entering MFMA cluster
      __builtin_amdgcn_s_setprio(1);
      #pragma unroll
      for (int mf2 = 0; mf2 < 4; ++mf2)
        #pragma unroll
        for (int nf2 = 0; nf2 < 2; ++nf2)
          #pragma unroll
          for (int kk = 0; kk < 2; ++kk)
            acc[mh * 4 + mf2][nh * 2 + nf2] = __builtin_amdgcn_mfma_f32_16x16x32_bf16(
                af[mf2][kk], bfr[nf2][kk], acc[mh * 4 + mf2][nh * 2 + nf2], 0, 0, 0);
      __builtin_amdgcn_s_setprio(0);
      if (p < 3) {
        __builtin_amdgcn_s_barrier();
      } else {
        asm volatile("s_waitcnt vmcnt(0)" ::: "memory");
        __builtin_amdgcn_s_barrier();
        __builtin_amdgcn_sched_barrier(0);
      }
    }
  }

  float bcol[4];
  #pragma unroll
  for (int nf = 0; nf < 4; nf++) bcol[nf] = bias[n0 + wn * 64 + nf * 16 + fr];

  if (MODE == 2) {
    // V^T store: out[((b*16+h)*64+d)*2048 + s], col=h*64+d, row=b*2048+s.
    #pragma unroll
    for (int mf = 0; mf < 8; mf++) {
      const int row0 = m0 + wm * 128 + mf * 16 + kg * 4;
      #pragma unroll
      for (int nf = 0; nf < 4; nf++) {
        const int col = n0 + wn * 64 + nf * 16 + fr;
        u16x4 o;
        #pragma unroll
        for (int r = 0; r < 4; r++) o[r] = f2bf(acc[mf][nf][r] + bcol[nf]);
        size_t idx = (((size_t)(col + ((row0 >> 11) << 10))) << 11) + (row0 & 2047);
        *(u16x4*)(Obf + idx) = o;
      }
    }
  } else {
    #pragma unroll
    for (int mf = 0; mf < 8; mf++)
      #pragma unroll
      for (int r = 0; r < 4; r++) {
        const int row = m0 + wm * 128 + mf * 16 + kg * 4 + r;
        #pragma unroll
        for (int nf = 0; nf < 4; nf++) {
          const int col = n0 + wn * 64 + nf * 16 + fr;
          Obf[(size_t)row * H_ + col] = f2bf((acc[mf][nf][r] + bcol[nf]) * scale);
        }
      }
  }
}

// grid (8,8,3): xcd = blockIdx.x (64 blocks/plane, 8|64); XCD x owns m_tiles [2x,2x+2)
__global__ __launch_bounds__(512, 2) void gemm_qkv256(const u16* __restrict__ xb, const u16* __restrict__ wt,
                                                      const float* __restrict__ b0, const float* __restrict__ b1,
                                                      const float* __restrict__ b2,
                                                      u16* __restrict__ QKo, u16* __restrict__ VTo) {
  // LDS lives HERE (one copy shared by both template instantiations)
  __shared__ u16 lA[2][256 * 64];
  __shared__ u16 lB[2][256 * 64];
  const int z = blockIdx.z;
  const int swz = (blockIdx.x << 3) + blockIdx.y;   // 0..63
  const int mt = swz >> 2, nt = swz & 3;
  const u16* A = xb + (size_t)z * MR_ * K_;
  const u16* Bt = wt + (size_t)z * H_ * K_;
  if (z == 2) {
    body256<2>(A, Bt, b2, 1.0f, VTo, mt, nt, &lA[0][0], &lB[0][0]);
  } else {
    const float* bias = z == 0 ? b0 : b1;
    // fold 1/sqrt(HD) AND log2(e) into Q so softmax uses raw v_exp_f32 (exp2)
    const float scale = z == 0 ? 0.18033688011112042f : 1.0f;
    body256<0>(A, Bt, bias, scale, QKo + (size_t)z * MR_ * H_, mt, nt, &lA[0][0], &lB[0][0]);
  }
}

// ---------------- 128x128 GEMM body (proven) -- used by gemm_out only ----------------
__device__ __forceinline__ void gemm_body_f32(const u16* __restrict__ A, const u16* __restrict__ Bt,
                                              const float* __restrict__ bias, float* __restrict__ Of,
                                              int m_tile, int n_tile) {
  __shared__ u16 ldsA[128 * 64];
  __shared__ u16 ldsB[128 * 64];
  const int tid = threadIdx.x;
  const int lane = tid & 63, wave = tid >> 6;
  const int wm = wave >> 1, wn = wave & 1;
  const int m0 = m_tile * 128, n0 = n_tile * 128;

  f32x4 acc[4][4] = {};

  const int srow = tid >> 3;                     // 0..31
  const int sslot = (tid & 7) ^ (srow & 7);      // logical k-slot to fetch (pre-swizzled source)
  const u16* ga = A + (size_t)(m0 + srow) * K_ + sslot * 8;
  const u16* gb = Bt + (size_t)(n0 + srow) * K_ + sslot * 8;
  u16* la = ldsA + tid * 8;
  u16* lb = ldsB + tid * 8;

  const int fr = lane & 15;   // fragment row (A: m, B: n)
  const int kg = lane >> 4;   // k-group 0..3

  for (int k0 = 0; k0 < K_; k0 += 64) {
    #pragma unroll
    for (int j = 0; j < 4; j++) gload16(ga + (size_t)(j * 32) * K_ + k0, la + j * 2048);
    #pragma unroll
    for (int j = 0; j < 4; j++) gload16(gb + (size_t)(j * 32) * K_ + k0, lb + j * 2048);
    __syncthreads();

    #pragma unroll
    for (int kk = 0; kk < 2; kk++) {
      const int ps = (((kk << 2) | kg) ^ (fr & 7)) * 8;   // swizzled read
      bf16x8 a[4], b[4];
      #pragma unroll
      for (int mf = 0; mf < 4; mf++)
        a[mf] = *(const bf16x8*)&ldsA[(wm * 64 + mf * 16 + fr) * 64 + ps];
      #pragma unroll
      for (int nf = 0; nf < 4; nf++)
        b[nf] = *(const bf16x8*)&ldsB[(wn * 64 + nf * 16 + fr) * 64 + ps];
      #pragma unroll
      for (int mf = 0; mf < 4; mf++)
        #pragma unroll
        for (int nf = 0; nf < 4; nf++)
          acc[mf][nf] = __builtin_amdgcn_mfma_f32_16x16x32_bf16(a[mf], b[nf], acc[mf][nf], 0, 0, 0);
    }
    __syncthreads();
  }

  float bcol[4];
  #pragma unroll
  for (int nf = 0; nf < 4; nf++) bcol[nf] = bias[n0 + wn * 64 + nf * 16 + fr];
  #pragma unroll
  for (int mf = 0; mf < 4; mf++)
    #pragma unroll
    for (int r = 0; r < 4; r++) {
      const int row = m0 + wm * 64 + mf * 16 + kg * 4 + r;
      #pragma unroll
      for (int nf = 0; nf < 4; nf++) {
        const int col = n0 + wn * 64 + nf * 16 + fr;
        Of[(size_t)row * H_ + col] = acc[mf][nf][r] + bcol[nf];
      }
    }
}

__global__ __launch_bounds__(256) void gemm_out(const u16* __restrict__ ctx, const u16* __restrict__ wot,
                                                const float* __restrict__ bo, float* __restrict__ out) {
  const int bid = blockIdx.x + (blockIdx.y << 3);      // 0..255
  const int swz = ((bid & 7) << 5) + (bid >> 3);       // XCD-chunked
  gemm_body_f32(ctx, wot, bo, out, swz >> 3, swz & 7);
}

// ---------------- flash attention: 8 waves, in-block split-KV ----------------
// Bank-conflict fix: swizzle widened to f(row) = (row&7) ^ ((row>>3)&3) -- the 32-row
// ds_read patterns (K: row=ql, V: row=dt*32+ql) previously 4-way-collided because rows
// differing by 8/16/24 shared a slot-quad (128B rows all start at bank 0). Applied on
// BOTH sides: staging source (sslot) and reads (fq). f(row+32j)=f(row) so one sslot
// covers both j-chunks and k0/k1 rows share fq.
__global__ __launch_bounds__(512, 4) void attn(const u16* __restrict__ qp, const u16* __restrict__ kp,
                                               const u16* __restrict__ vt, u16* __restrict__ ctx) {
  __shared__ u16 Kl[2][2][64 * 64];   // [group][buf][s][d-slot], phys_slot = slot ^ f(s)
  __shared__ u16 Vl[2][2][64 * 64];   // [group][buf][d][s-slot], phys_slot = slot ^ f(d)
  __shared__ float mlbuf[2][4][32][2];
  // XCD-chunked bijective swizzle: 16 q-tiles per bh stay on one XCD
  const int bid = blockIdx.x + (blockIdx.y << 4);
  const int swz = ((bid & 7) << 6) + (bid >> 3);
  const int bh = swz >> 4;
  const int b = bh >> 4, h = bh & 15;
  const int q0 = (swz & 15) * 128;
  const int tid = threadIdx.x;
  const int g0 = tid >> 8;            // kv-half group
  const int gt = tid & 255;           // thread id within group
  const int w = (tid >> 6) & 3;       // wave within group
  const int l = tid & 63;
  const int ql = l & 31, hi = l >> 5;

  const u16* Q   = qp + (size_t)b * S_ * H_ + h * HD_;
  const u16* Kb  = kp + (size_t)b * S_ * H_ + h * HD_;
  const u16* Vtb = vt + (size_t)bh * HD_ * S_;
  u16* O = ctx + (size_t)b * S_ * H_ + h * HD_;

  const int srow = gt >> 3;                   // 0..31
  // widened swizzle: f(srow) = (srow&7) ^ ((srow>>3)&3)
  const int sslot = (gt & 7) ^ ((srow & 7) ^ ((srow >> 3) & 3));
  const int sbase = g0 << 10;                 // this group's kv offset

  // Q fragments hoisted (loop-invariant): lane holds Q[q=q0+w*32+ql][d=ds*16+hi*8+j]
  const u16* Qrow = Q + (size_t)(q0 + w * 32 + ql) * H_;
  bf16x8 qf[4];
  #pragma unroll
  for (int ds = 0; ds < 4; ds++)
    qf[ds] = *(const bf16x8*)&Qrow[ds * 16 + hi * 8];

  // read-side swizzle term for rows ql / 32+ql (K) and dt*32+ql (V): all equal f(ql)
  const int fq = (ql & 7) ^ ((ql >> 3) & 3);

  f32x16 oacc0 = {}, oacc1 = {};       // C[q][d], dt=0,1 ; rows q=(r&3)+8*(r>>2)+4*hi, col d=dt*32+ql
  float m_run = -1e30f, l_run = 0.f;   // state for q-col = ql (mirrored on lane pair)

  // prologue: stage tile 0 into buffer 0
  #pragma unroll
  for (int j = 0; j < 2; j++) {
    gload16(Kb + (size_t)(sbase + srow + 32 * j) * H_ + sslot * 8,
            &Kl[g0][0][0] + j * 2048 + gt * 8);
    gload16(Vtb + (size_t)(srow + 32 * j) * S_ + sbase + sslot * 8,
            &Vl[g0][0][0] + j * 2048 + gt * 8);
  }

  for (int it = 0; it < 16; ++it) {
    const int s0 = sbase + it * 64, cur = it & 1;
    __syncthreads();   // staged tile visible
    if (it + 1 < 16) {
      #pragma unroll
      for (int j = 0; j < 2; j++) {
        gload16(Kb + (size_t)(s0 + 64 + srow + 32 * j) * H_ + sslot * 8,
                &Kl[g0][cur ^ 1][0] + j * 2048 + gt * 8);
        gload16(Vtb + (size_t)(srow + 32 * j) * S_ + s0 + 64 + sslot * 8,
                &Vl[g0][cur ^ 1][0] + j * 2048 + gt * 8);
      }
    }
    // swapped QK^T: sc_st = mfma32(K_frag, Q_frag). D[s][q]: q=l&31, s=st*32+(r&3)+8*(r>>2)+4*hi
    f32x16 sc0 = {}, sc1 = {};
    __builtin_amdgcn_s_setprio(1);
    #pragma unroll
    for (int ds = 0; ds < 4; ds++) {
      const int sl = ((ds * 2 + hi) ^ fq) << 3;
      bf16x8 k0 = *(const bf16x8*)&Kl[g0][cur][ql * 64 + sl];
      bf16x8 k1 = *(const bf16x8*)&Kl[g0][cur][(32 + ql) * 64 + sl];
      sc0 = __builtin_amdgcn_mfma_f32_32x32x16_bf16(k0, qf[ds], sc0, 0, 0, 0);
      sc1 = __builtin_amdgcn_mfma_f32_32x32x16_bf16(k1, qf[ds], sc1, 0, 0, 0);
    }
    __builtin_amdgcn_s_setprio(0);
    // tree max over 32 in-register scores, then one cross-half reduce
    float t4[8];
    #pragma unroll
    for (int g = 0; g < 4; g++) {
      t4[g]     = fmaxf(fmaxf(sc0[4*g], sc0[4*g+1]), fmaxf(sc0[4*g+2], sc0[4*g+3]));
      t4[4 + g] = fmaxf(fmaxf(sc1[4*g], sc1[4*g+1]), fmaxf(sc1[4*g+2], sc1[4*g+3]));
    }
    float tmax = fmaxf(fmaxf(fmaxf(t4[0], t4[1]), fmaxf(t4[2], t4[3])),
                       fmaxf(fmaxf(t4[4], t4[5]), fmaxf(t4[6], t4[7])));
    tmax = fmaxf(tmax, __shfl_xor(tmax, 32, 64));
    // defer-max (THR=8 log2 units)
    if (!__all(tmax <= m_run + 8.0f)) {
      const float mn = fmaxf(m_run, tmax);
      const float sf = __builtin_amdgcn_exp2f(m_run - mn);
      m_run = mn;
      l_run *= sf;
      #pragma unroll
      for (int r = 0; r < 16; r++) {
        const float sfq = __shfl(sf, (r & 3) + 8 * (r >> 2) + 4 * hi, 64);
        oacc0[r] *= sfq;
        oacc1[r] *= sfq;
      }
    }
    // p = exp2(sc - m_run); psum; cvt_pk packs (pk[st][g] covers s' = 8g+4*hi+(0..3))
    float ps4[8];
    #pragma unroll
    for (int g = 0; g < 4; g++) {
      #pragma unroll
      for (int m = 0; m < 4; m++) {
        sc0[4*g+m] = __builtin_amdgcn_exp2f(sc0[4*g+m] - m_run);
        sc1[4*g+m] = __builtin_amdgcn_exp2f(sc1[4*g+m] - m_run);
      }
      ps4[g]     = (sc0[4*g] + sc0[4*g+1]) + (sc0[4*g+2] + sc0[4*g+3]);
      ps4[4 + g] = (sc1[4*g] + sc1[4*g+1]) + (sc1[4*g+2] + sc1[4*g+3]);
    }
    float psum = ((ps4[0] + ps4[1]) + (ps4[2] + ps4[3])) + ((ps4[4] + ps4[5]) + (ps4[6] + ps4[7]));
    psum += __shfl_xor(psum, 32, 64);
    l_run += psum;
    uint2 pk0[4], pk1[4];
    #pragma unroll
    for (int g = 0; g < 4; g++) {
      pk0[g].x = cvtpk(sc0[4*g], sc0[4*g+1]);  pk0[g].y = cvtpk(sc0[4*g+2], sc0[4*g+3]);
      pk1[g].x = cvtpk(sc1[4*g], sc1[4*g+1]);  pk1[g].y = cvtpk(sc1[4*g+2], sc1[4*g+3]);
    }
    // PV: A = P[q][s] assembled via permlane32_swap; B = V^T[d][s] from LDS
    __builtin_amdgcn_s_setprio(1);
    #pragma unroll
    for (int ks = 0; ks < 4; ks++) {
      const int ga = (ks & 1) * 2;
      unsigned x0, y0, x1, y1;
      if (ks < 2) { x0 = pk0[ga].x; y0 = pk0[ga].y; x1 = pk0[ga+1].x; y1 = pk0[ga+1].y; }
      else        { x0 = pk1[ga].x; y0 = pk1[ga].y; x1 = pk1[ga+1].x; y1 = pk1[ga+1].y; }
      plswap(x0, x1);   // x0 -> j0..1 merged, x1 -> j4..5
      plswap(y0, y1);   // y0 -> j2..3,        y1 -> j6..7
      u32x4 fu = { x0, y0, x1, y1 };
      const bf16x8 pfrag = __builtin_bit_cast(bf16x8, fu);
      #pragma unroll
      for (int dt = 0; dt < 2; dt++) {
        const int d = dt * 32 + ql;
        bf16x8 vf = *(const bf16x8*)&Vl[g0][cur][d * 64 + (((ks * 2 + hi) ^ fq) << 3)];
        if (dt == 0) oacc0 = __builtin_amdgcn_mfma_f32_32x32x16_bf16(pfrag, vf, oacc0, 0, 0, 0);
        else         oacc1 = __builtin_amdgcn_mfma_f32_32x32x16_bf16(pfrag, vf, oacc1, 0, 0, 0);
      }
    }
    __builtin_amdgcn_s_setprio(0);
  }

  // -------- merge the two kv-half partials --------
  if (l < 32) { mlbuf[g0][w][ql][0] = m_run; mlbuf[g0][w][ql][1] = l_run; }
  __syncthreads();   // ml visible; also: all LDS K/V reads done -> Kl reusable
  const float m_o = mlbuf[g0 ^ 1][w][ql][0];
  const float l_o = mlbuf[g0 ^ 1][w][ql][1];
  const float m_tot = fmaxf(m_run, m_o);
  const float a_s = __builtin_amdgcn_exp2f(m_run - m_tot);
  const float rinv = 1.0f / (l_run * a_s + l_o * __builtin_amdgcn_exp2f(m_o - m_tot));
  // broadcast BOTH a_s and rinv to the oacc row owners (row q=qi, NOT ql)
  float ar[16], rr[16];
  #pragma unroll
  for (int r = 0; r < 16; r++) {
    const int qi = (r & 3) + 8 * (r >> 2) + 4 * hi;
    ar[r] = __shfl(a_s, qi, 64);
    rr[r] = __shfl(rinv, qi, 64);
  }

  float* cb = (float*)(&Kl[0][0][0]);          // 32 KB scratch (retired K tiles)
  float* cw = cb + w * 2048 + l;
  if (g0 == 1) {
    #pragma unroll
    for (int r = 0; r < 16; r++) {
      cw[r * 64]        = oacc0[r] * ar[r];
      cw[(16 + r) * 64] = oacc1[r] * ar[r];
    }
  }
  __syncthreads();
  if (g0 == 0) {
    #pragma unroll
    for (int r = 0; r < 16; r++) {
      const int qi = (r & 3) + 8 * (r >> 2) + 4 * hi;
      const int row = q0 + w * 32 + qi;
      O[(size_t)row * H_ + ql]      = f2bf((oacc0[r] * ar[r] + cw[r * 64]) * rr[r]);
      O[(size_t)row * H_ + 32 + ql] = f2bf((oacc1[r] * ar[r] + cw[(16 + r) * 64]) * rr[r]);
    }
  }
}

extern "C" void kernel_launch(void* const* d_in, const int* in_sizes, int n_in,
                              void* d_out, int out_size, void* d_ws, size_t ws_size,
                              hipStream_t stream) {
  const float* q  = (const float*)d_in[0];
  const float* k  = (const float*)d_in[1];
  const float* v  = (const float*)d_in[2];
  const float* Wq = (const float*)d_in[3];
  const float* bq = (const float*)d_in[4];
  const float* Wk = (const float*)d_in[5];
  const float* bk = (const float*)d_in[6];
  const float* Wv = (const float*)d_in[7];
  const float* bv = (const float*)d_in[8];
  const float* Wo = (const float*)d_in[9];
  const float* bo = (const float*)d_in[10];
  float* out = (float*)d_out;

  char* ws = (char*)d_ws;
  const size_t MB = 1024 * 1024;
  u16* xb   = (u16*)(ws);             // q,k,v bf16: 3 x 8MB      [0,24)
  u16* wt   = (u16*)(ws + 24 * MB);   // 4 x 2MB transposed W     [24,32)
  u16* qkp  = (u16*)(ws + 32 * MB);   // qp,kp: 2 x 8MB           [32,48)
  u16* vtp  = (u16*)(ws + 48 * MB);   // V^T [bh][d][s]: 8MB      [48,56)
  u16* ctx  = (u16*)(ws);             // reuse xb region after gemm_qkv

  prep      <<<dim3(16384),     256, 0, stream>>>(q, k, v, Wq, Wk, Wv, Wo, xb, wt);
  gemm_qkv256<<<dim3(8, 8, 3),  512, 0, stream>>>(xb, wt, bq, bk, bv, qkp, vtp);
  attn      <<<dim3(16, 32),    512, 0, stream>>>(qkp, qkp + (size_t)MR_ * H_, vtp, ctx);
  gemm_out  <<<dim3(8, 32, 1),  256, 0, stream>>>(ctx, wt + (size_t)3 * H_ * K_, bo, out);
}